// Round 1
// baseline (2595.123 us; speedup 1.0000x reference)
//
#include <hip/hip_runtime.h>
#include <hip/hip_bf16.h>

// Encoder: B=4, S=2048, D=256, H=8, DK=32, DFF=1024, fp32 in/out.
// All projections are relu(x @ W^T). Two identical blocks.

#define MROWS 8192   // B*S
#define DMODEL 256
#define SEQ 2048
#define NHEAD 8
#define HDIM 32
#define LN_EPS 1e-5f

// ---------------- GEMM: C = relu(A @ W^T) (+ res) ----------------
// A: [M x K] row-major, W: [N x K] row-major, C/res: [M x N]
// Tile 64x64, BK=16, 256 threads, 4x4 accum per thread.
__global__ __launch_bounds__(256) void gemm_relu_kernel(
    const float* __restrict__ A, const float* __restrict__ W,
    const float* __restrict__ res, float* __restrict__ C,
    int N, int K) {
  __shared__ float As[16][64];
  __shared__ float Ws[16][64];
  const int tid = threadIdx.x;
  const int m0 = blockIdx.y * 64;
  const int n0 = blockIdx.x * 64;
  const int tx = tid & 15, ty = tid >> 4;
  const int lrow = tid >> 2;          // 0..63
  const int lc4 = (tid & 3) * 4;      // 0,4,8,12

  float acc[4][4] = {};

  for (int k0 = 0; k0 < K; k0 += 16) {
    float4 a = *(const float4*)(A + (size_t)(m0 + lrow) * K + k0 + lc4);
    float4 w = *(const float4*)(W + (size_t)(n0 + lrow) * K + k0 + lc4);
    As[lc4 + 0][lrow] = a.x; As[lc4 + 1][lrow] = a.y;
    As[lc4 + 2][lrow] = a.z; As[lc4 + 3][lrow] = a.w;
    Ws[lc4 + 0][lrow] = w.x; Ws[lc4 + 1][lrow] = w.y;
    Ws[lc4 + 2][lrow] = w.z; Ws[lc4 + 3][lrow] = w.w;
    __syncthreads();
#pragma unroll
    for (int kk = 0; kk < 16; kk++) {
      float ar[4], wr[4];
#pragma unroll
      for (int i = 0; i < 4; i++) ar[i] = As[kk][ty * 4 + i];
#pragma unroll
      for (int j = 0; j < 4; j++) wr[j] = Ws[kk][tx * 4 + j];
#pragma unroll
      for (int i = 0; i < 4; i++)
#pragma unroll
        for (int j = 0; j < 4; j++) acc[i][j] += ar[i] * wr[j];
    }
    __syncthreads();
  }

#pragma unroll
  for (int i = 0; i < 4; i++) {
    const int m = m0 + ty * 4 + i;
    const int n = n0 + tx * 4;
    float4 v;
    v.x = fmaxf(acc[i][0], 0.f);
    v.y = fmaxf(acc[i][1], 0.f);
    v.z = fmaxf(acc[i][2], 0.f);
    v.w = fmaxf(acc[i][3], 0.f);
    if (res) {
      float4 r = *(const float4*)(res + (size_t)m * N + n);
      v.x += r.x; v.y += r.y; v.z += r.z; v.w += r.w;
    }
    *(float4*)(C + (size_t)m * N + n) = v;
  }
}

// ---------------- Flash attention (fp32) ----------------
// Q/K/V layout: [B*S, D] with head h at columns h*32..h*32+31.
// 1 thread = 1 query row. K/V tiles (64x32) in LDS, broadcast reads.
__global__ __launch_bounds__(128) void attn_kernel(
    const float* __restrict__ Q, const float* __restrict__ K,
    const float* __restrict__ V, float* __restrict__ O) {
  const int bh = blockIdx.y;
  const int b = bh >> 3, h = bh & 7;
  const int qrow = blockIdx.x * 128 + threadIdx.x;
  const size_t base = (size_t)b * SEQ * DMODEL + h * HDIM;

  float qr[32];
  const float* qp = Q + base + (size_t)qrow * DMODEL;
#pragma unroll
  for (int i = 0; i < 8; i++) {
    float4 t = *(const float4*)(qp + i * 4);
    qr[i * 4 + 0] = t.x; qr[i * 4 + 1] = t.y;
    qr[i * 4 + 2] = t.z; qr[i * 4 + 3] = t.w;
  }

  float o[32] = {};
  float m = -1e30f, l = 0.f;
  const float scale = 0.17677669529663687f;  // 1/sqrt(32)

  __shared__ float Ks[64][32];
  __shared__ float Vs[64][32];

  for (int kt = 0; kt < SEQ; kt += 64) {
    __syncthreads();
#pragma unroll
    for (int i = 0; i < 4; i++) {
      int li = threadIdx.x + i * 128;  // 0..511
      int row = li >> 3, c4 = (li & 7) * 4;
      *(float4*)&Ks[row][c4] =
          *(const float4*)(K + base + (size_t)(kt + row) * DMODEL + c4);
      *(float4*)&Vs[row][c4] =
          *(const float4*)(V + base + (size_t)(kt + row) * DMODEL + c4);
    }
    __syncthreads();

    float sc[64];
    float tmax = -1e30f;
#pragma unroll
    for (int kk = 0; kk < 64; kk++) {
      float s = 0.f;
#pragma unroll
      for (int d = 0; d < 32; d++) s += qr[d] * Ks[kk][d];
      s *= scale;
      sc[kk] = s;
      tmax = fmaxf(tmax, s);
    }
    float mn = fmaxf(m, tmax);
    float corr = __expf(m - mn);
    l *= corr;
#pragma unroll
    for (int d = 0; d < 32; d++) o[d] *= corr;
#pragma unroll
    for (int kk = 0; kk < 64; kk++) {
      float p = __expf(sc[kk] - mn);
      l += p;
#pragma unroll
      for (int d = 0; d < 32; d++) o[d] += p * Vs[kk][d];
    }
    m = mn;
  }

  float inv = 1.f / l;
  float* op = O + base + (size_t)qrow * DMODEL;
#pragma unroll
  for (int i = 0; i < 8; i++) {
    float4 t;
    t.x = o[i * 4 + 0] * inv; t.y = o[i * 4 + 1] * inv;
    t.z = o[i * 4 + 2] * inv; t.w = o[i * 4 + 3] * inv;
    *(float4*)(op + i * 4) = t;
  }
}

// ---------------- LayerNorm over last dim (256) ----------------
// 1 wave per row; lane handles 4 contiguous floats.
__global__ __launch_bounds__(256) void ln_kernel(
    const float* __restrict__ X, const float* __restrict__ g,
    const float* __restrict__ b, float* __restrict__ Y) {
  const int wid = (blockIdx.x * blockDim.x + threadIdx.x) >> 6;  // row
  const int lane = threadIdx.x & 63;
  const float* x = X + (size_t)wid * DMODEL;
  float4 v = *(const float4*)(x + lane * 4);
  float s = v.x + v.y + v.z + v.w;
  float s2 = v.x * v.x + v.y * v.y + v.z * v.z + v.w * v.w;
#pragma unroll
  for (int off = 32; off >= 1; off >>= 1) {
    s += __shfl_xor(s, off, 64);
    s2 += __shfl_xor(s2, off, 64);
  }
  const float mu = s * (1.f / DMODEL);
  const float var = s2 * (1.f / DMODEL) - mu * mu;
  const float inv = rsqrtf(var + LN_EPS);
  float4 gv = *(const float4*)(g + lane * 4);
  float4 bv = *(const float4*)(b + lane * 4);
  float4 out;
  out.x = (v.x - mu) * inv * gv.x + bv.x;
  out.y = (v.y - mu) * inv * gv.y + bv.y;
  out.z = (v.z - mu) * inv * gv.z + bv.z;
  out.w = (v.w - mu) * inv * gv.w + bv.w;
  *(float4*)(Y + (size_t)wid * DMODEL + lane * 4) = out;
}

extern "C" void kernel_launch(void* const* d_in, const int* in_sizes, int n_in,
                              void* d_out, int out_size, void* d_ws, size_t ws_size,
                              hipStream_t stream) {
  const float* x   = (const float*)d_in[0];
  const float* W11 = (const float*)d_in[1];
  const float* W12 = (const float*)d_in[2];
  const float* W13 = (const float*)d_in[3];
  const float* W14 = (const float*)d_in[4];
  const float* W21 = (const float*)d_in[5];
  const float* W22 = (const float*)d_in[6];
  const float* W23 = (const float*)d_in[7];
  const float* W24 = (const float*)d_in[8];
  const float* Wf11 = (const float*)d_in[9];
  const float* Wf21 = (const float*)d_in[10];
  const float* Wf12 = (const float*)d_in[11];
  const float* Wf22 = (const float*)d_in[12];
  const float* g1 = (const float*)d_in[13];
  const float* b1 = (const float*)d_in[14];
  const float* g2 = (const float*)d_in[15];
  const float* b2 = (const float*)d_in[16];
  const float* g3 = (const float*)d_in[17];
  const float* b3 = (const float*)d_in[18];
  const float* g4 = (const float*)d_in[19];
  const float* b4 = (const float*)d_in[20];

  float* out = (float*)d_out;
  float* ws = (float*)d_ws;
  const size_t NM = (size_t)MROWS * DMODEL;  // 2.10M floats
  float* B0 = ws;
  float* B1 = ws + NM;
  float* B2 = ws + 2 * NM;
  float* B3 = ws + 3 * NM;
  float* BF = ws + 4 * NM;  // 8192x1024
  float* B4 = out;          // block-1 output lives in d_out temporarily

  auto gemm = [&](const float* A, const float* W, const float* res, float* C,
                  int N, int K) {
    dim3 grid(N / 64, MROWS / 64);
    gemm_relu_kernel<<<grid, 256, 0, stream>>>(A, W, res, C, N, K);
  };
  auto attn = [&](const float* Q, const float* K, const float* V, float* O) {
    attn_kernel<<<dim3(SEQ / 128, 32), 128, 0, stream>>>(Q, K, V, O);
  };
  auto ln = [&](const float* X, const float* gm, const float* bt, float* Y) {
    ln_kernel<<<MROWS / 4, 256, 0, stream>>>(X, gm, bt, Y);
  };

  // ---- Block 1 (input x) ----
  gemm(x, W11, nullptr, B0, 256, 256);     // q
  gemm(x, W12, nullptr, B1, 256, 256);     // k
  gemm(x, W13, nullptr, B2, 256, 256);     // v
  attn(B0, B1, B2, B3);                    // o
  gemm(B3, W14, x, B0, 256, 256);          // x1 = relu(o@Wo)+x
  ln(B0, g1, b1, B1);                      // x1n
  gemm(B1, Wf11, nullptr, BF, 1024, 256);  // f = relu(x1n@Wf1)
  gemm(BF, Wf21, B1, B2, 256, 1024);       // x2 = relu(f@Wf2)+x1n
  ln(B2, g2, b2, B4);                      // block-1 out

  // ---- Block 2 (input B4) ----
  gemm(B4, W21, nullptr, B0, 256, 256);
  gemm(B4, W22, nullptr, B1, 256, 256);
  gemm(B4, W23, nullptr, B2, 256, 256);
  attn(B0, B1, B2, B3);
  gemm(B3, W24, B4, B0, 256, 256);
  ln(B0, g3, b3, B1);
  gemm(B1, Wf12, nullptr, BF, 1024, 256);
  gemm(BF, Wf22, B1, B2, 256, 1024);
  ln(B2, g4, b4, out);
}

// Round 2
// 1618.584 us; speedup vs baseline: 1.6033x; 1.6033x over previous
//
#include <hip/hip_runtime.h>
#include <hip/hip_bf16.h>

// Encoder: B=4, S=2048, D=256, H=8, DK=32, DFF=1024, fp32 in/out.
// All projections are relu(x @ W^T). Two identical blocks.

#define MROWS 8192   // B*S
#define DMODEL 256
#define SEQ 2048
#define NHEAD 8
#define HDIM 32
#define LN_EPS 1e-5f

// ---------------- GEMM: C = relu(A @ W^T) (+ res) ----------------
// A: [M x K] row-major, W: [N x K] row-major, C/res: [M x N]
// Tile 64x64, BK=16, 256 threads, 4x4 accum per thread.
__global__ __launch_bounds__(256) void gemm_relu_kernel(
    const float* __restrict__ A, const float* __restrict__ W,
    const float* __restrict__ res, float* __restrict__ C,
    int N, int K) {
  __shared__ float As[16][64];
  __shared__ float Ws[16][64];
  const int tid = threadIdx.x;
  const int m0 = blockIdx.y * 64;
  const int n0 = blockIdx.x * 64;
  const int tx = tid & 15, ty = tid >> 4;
  const int lrow = tid >> 2;          // 0..63
  const int lc4 = (tid & 3) * 4;      // 0,4,8,12

  float acc[4][4] = {};

  for (int k0 = 0; k0 < K; k0 += 16) {
    float4 a = *(const float4*)(A + (size_t)(m0 + lrow) * K + k0 + lc4);
    float4 w = *(const float4*)(W + (size_t)(n0 + lrow) * K + k0 + lc4);
    As[lc4 + 0][lrow] = a.x; As[lc4 + 1][lrow] = a.y;
    As[lc4 + 2][lrow] = a.z; As[lc4 + 3][lrow] = a.w;
    Ws[lc4 + 0][lrow] = w.x; Ws[lc4 + 1][lrow] = w.y;
    Ws[lc4 + 2][lrow] = w.z; Ws[lc4 + 3][lrow] = w.w;
    __syncthreads();
#pragma unroll
    for (int kk = 0; kk < 16; kk++) {
      float ar[4], wr[4];
#pragma unroll
      for (int i = 0; i < 4; i++) ar[i] = As[kk][ty * 4 + i];
#pragma unroll
      for (int j = 0; j < 4; j++) wr[j] = Ws[kk][tx * 4 + j];
#pragma unroll
      for (int i = 0; i < 4; i++)
#pragma unroll
        for (int j = 0; j < 4; j++) acc[i][j] += ar[i] * wr[j];
    }
    __syncthreads();
  }

#pragma unroll
  for (int i = 0; i < 4; i++) {
    const int m = m0 + ty * 4 + i;
    const int n = n0 + tx * 4;
    float4 v;
    v.x = fmaxf(acc[i][0], 0.f);
    v.y = fmaxf(acc[i][1], 0.f);
    v.z = fmaxf(acc[i][2], 0.f);
    v.w = fmaxf(acc[i][3], 0.f);
    if (res) {
      float4 r = *(const float4*)(res + (size_t)m * N + n);
      v.x += r.x; v.y += r.y; v.z += r.z; v.w += r.w;
    }
    *(float4*)(C + (size_t)m * N + n) = v;
  }
}

// ---------------- Flash attention (fp32), KV-split ----------------
// Q/K/V layout: [B*S, D] with head h at columns h*32..h*32+31.
// 1 thread = 1 query row; blockIdx.z = KV slice. Writes UNNORMALIZED
// partial o plus (m, l) per row; combine kernel merges slices.
__global__ __launch_bounds__(128) void attn_split_kernel(
    const float* __restrict__ Q, const float* __restrict__ K,
    const float* __restrict__ V, float* __restrict__ oP,
    float* __restrict__ mP, float* __restrict__ lP, int nkeys) {
  const int bh = blockIdx.y;
  const int b = bh >> 3, h = bh & 7;
  const int p = blockIdx.z;
  const int qrow = blockIdx.x * 128 + threadIdx.x;
  const size_t base = (size_t)b * SEQ * DMODEL + h * HDIM;

  float qr[32];
  const float* qp = Q + base + (size_t)qrow * DMODEL;
#pragma unroll
  for (int i = 0; i < 8; i++) {
    float4 t = *(const float4*)(qp + i * 4);
    qr[i * 4 + 0] = t.x; qr[i * 4 + 1] = t.y;
    qr[i * 4 + 2] = t.z; qr[i * 4 + 3] = t.w;
  }

  float o[32] = {};
  float m = -1e30f, l = 0.f;
  const float scale = 0.17677669529663687f;  // 1/sqrt(32)

  __shared__ float Ks[64][32];
  __shared__ float Vs[64][32];

  const int kbeg = p * nkeys;
  const int kend = kbeg + nkeys;
  for (int kt = kbeg; kt < kend; kt += 64) {
    __syncthreads();
#pragma unroll
    for (int i = 0; i < 4; i++) {
      int li = threadIdx.x + i * 128;  // 0..511
      int row = li >> 3, c4 = (li & 7) * 4;
      *(float4*)&Ks[row][c4] =
          *(const float4*)(K + base + (size_t)(kt + row) * DMODEL + c4);
      *(float4*)&Vs[row][c4] =
          *(const float4*)(V + base + (size_t)(kt + row) * DMODEL + c4);
    }
    __syncthreads();

    float sc[64];
    float tmax = -1e30f;
#pragma unroll
    for (int kk = 0; kk < 64; kk++) {
      float s = 0.f;
#pragma unroll
      for (int d = 0; d < 32; d++) s += qr[d] * Ks[kk][d];
      s *= scale;
      sc[kk] = s;
      tmax = fmaxf(tmax, s);
    }
    float mn = fmaxf(m, tmax);
    float corr = __expf(m - mn);
    l *= corr;
#pragma unroll
    for (int d = 0; d < 32; d++) o[d] *= corr;
#pragma unroll
    for (int kk = 0; kk < 64; kk++) {
      float pr = __expf(sc[kk] - mn);
      l += pr;
#pragma unroll
      for (int d = 0; d < 32; d++) o[d] += pr * Vs[kk][d];
    }
    m = mn;
  }

  const size_t sidx = ((size_t)p * 32 + bh) * SEQ + qrow;
  mP[sidx] = m;
  lP[sidx] = l;
  float* op = oP + sidx * 32;
#pragma unroll
  for (int i = 0; i < 8; i++) {
    float4 t;
    t.x = o[i * 4 + 0]; t.y = o[i * 4 + 1];
    t.z = o[i * 4 + 2]; t.w = o[i * 4 + 3];
    *(float4*)(op + i * 4) = t;
  }
}

// Merge NS partial flash states -> O[b, qrow, h*32..]
template <int NS>
__global__ __launch_bounds__(256) void attn_combine_kernel(
    const float* __restrict__ oP, const float* __restrict__ mP,
    const float* __restrict__ lP, float* __restrict__ O) {
  const int t = blockIdx.x * blockDim.x + threadIdx.x;  // 0..65535
  const int bh = t >> 11;
  const int qrow = t & 2047;
  const int b = bh >> 3, h = bh & 7;

  float mv[NS], lv[NS];
  float mmax = -1e30f;
#pragma unroll
  for (int pp = 0; pp < NS; pp++) {
    const size_t sidx = ((size_t)pp * 32 + bh) * SEQ + qrow;
    mv[pp] = mP[sidx];
    lv[pp] = lP[sidx];
    mmax = fmaxf(mmax, mv[pp]);
  }
  float lsum = 0.f;
  float w[NS];
#pragma unroll
  for (int pp = 0; pp < NS; pp++) {
    w[pp] = __expf(mv[pp] - mmax);
    lsum += lv[pp] * w[pp];
  }
  const float inv = 1.f / lsum;

  float acc[32] = {};
#pragma unroll
  for (int pp = 0; pp < NS; pp++) {
    const float* op = oP + (((size_t)pp * 32 + bh) * SEQ + qrow) * 32;
#pragma unroll
    for (int i = 0; i < 8; i++) {
      float4 v = *(const float4*)(op + i * 4);
      acc[i * 4 + 0] += v.x * w[pp];
      acc[i * 4 + 1] += v.y * w[pp];
      acc[i * 4 + 2] += v.z * w[pp];
      acc[i * 4 + 3] += v.w * w[pp];
    }
  }
  float* outp = O + (size_t)b * SEQ * DMODEL + (size_t)qrow * DMODEL + h * HDIM;
#pragma unroll
  for (int i = 0; i < 8; i++) {
    float4 v;
    v.x = acc[i * 4 + 0] * inv; v.y = acc[i * 4 + 1] * inv;
    v.z = acc[i * 4 + 2] * inv; v.w = acc[i * 4 + 3] * inv;
    *(float4*)(outp + i * 4) = v;
  }
}

// ---------------- LayerNorm over last dim (256) ----------------
__global__ __launch_bounds__(256) void ln_kernel(
    const float* __restrict__ X, const float* __restrict__ g,
    const float* __restrict__ b, float* __restrict__ Y) {
  const int wid = (blockIdx.x * blockDim.x + threadIdx.x) >> 6;  // row
  const int lane = threadIdx.x & 63;
  const float* x = X + (size_t)wid * DMODEL;
  float4 v = *(const float4*)(x + lane * 4);
  float s = v.x + v.y + v.z + v.w;
  float s2 = v.x * v.x + v.y * v.y + v.z * v.z + v.w * v.w;
#pragma unroll
  for (int off = 32; off >= 1; off >>= 1) {
    s += __shfl_xor(s, off, 64);
    s2 += __shfl_xor(s2, off, 64);
  }
  const float mu = s * (1.f / DMODEL);
  const float var = s2 * (1.f / DMODEL) - mu * mu;
  const float inv = rsqrtf(var + LN_EPS);
  float4 gv = *(const float4*)(g + lane * 4);
  float4 bv = *(const float4*)(b + lane * 4);
  float4 out;
  out.x = (v.x - mu) * inv * gv.x + bv.x;
  out.y = (v.y - mu) * inv * gv.y + bv.y;
  out.z = (v.z - mu) * inv * gv.z + bv.z;
  out.w = (v.w - mu) * inv * gv.w + bv.w;
  *(float4*)(Y + (size_t)wid * DMODEL + lane * 4) = out;
}

extern "C" void kernel_launch(void* const* d_in, const int* in_sizes, int n_in,
                              void* d_out, int out_size, void* d_ws, size_t ws_size,
                              hipStream_t stream) {
  const float* x   = (const float*)d_in[0];
  const float* W11 = (const float*)d_in[1];
  const float* W12 = (const float*)d_in[2];
  const float* W13 = (const float*)d_in[3];
  const float* W14 = (const float*)d_in[4];
  const float* W21 = (const float*)d_in[5];
  const float* W22 = (const float*)d_in[6];
  const float* W23 = (const float*)d_in[7];
  const float* W24 = (const float*)d_in[8];
  const float* Wf11 = (const float*)d_in[9];
  const float* Wf21 = (const float*)d_in[10];
  const float* Wf12 = (const float*)d_in[11];
  const float* Wf22 = (const float*)d_in[12];
  const float* g1 = (const float*)d_in[13];
  const float* b1 = (const float*)d_in[14];
  const float* g2 = (const float*)d_in[15];
  const float* b2 = (const float*)d_in[16];
  const float* g3 = (const float*)d_in[17];
  const float* b3 = (const float*)d_in[18];
  const float* g4 = (const float*)d_in[19];
  const float* b4 = (const float*)d_in[20];

  float* out = (float*)d_out;
  float* ws = (float*)d_ws;
  const size_t NM = (size_t)MROWS * DMODEL;  // 2.10M floats
  float* B0 = ws;
  float* B1 = ws + NM;
  float* B2 = ws + 2 * NM;
  float* B3 = ws + 3 * NM;
  float* BF = ws + 4 * NM;  // 8192x1024 == 4*NM floats
  float* B4 = out;          // block-1 output lives in d_out temporarily

  // Attention split scratch: oP reuses BF (not live during attention);
  // m/l go right after BF's used portion (nsplit*NM floats).
  const size_t ML = (size_t)32 * SEQ;  // 65536 per split
  int nsplit = 4;
  {
    size_t need = (8 * NM + (size_t)nsplit * 2 * ML) * sizeof(float);
    if (ws_size < need) nsplit = 1;
  }
  float* oP = BF;
  float* mP = BF + (size_t)nsplit * NM;
  float* lP = mP + (size_t)nsplit * ML;

  auto gemm = [&](const float* A, const float* W, const float* res, float* C,
                  int N, int K) {
    dim3 grid(N / 64, MROWS / 64);
    gemm_relu_kernel<<<grid, 256, 0, stream>>>(A, W, res, C, N, K);
  };
  auto attn = [&](const float* Q, const float* K, const float* V, float* O) {
    dim3 grid(SEQ / 128, 32, nsplit);
    attn_split_kernel<<<grid, 128, 0, stream>>>(Q, K, V, oP, mP, lP,
                                                SEQ / nsplit);
    if (nsplit == 4)
      attn_combine_kernel<4><<<65536 / 256, 256, 0, stream>>>(oP, mP, lP, O);
    else
      attn_combine_kernel<1><<<65536 / 256, 256, 0, stream>>>(oP, mP, lP, O);
  };
  auto ln = [&](const float* X, const float* gm, const float* bt, float* Y) {
    ln_kernel<<<MROWS / 4, 256, 0, stream>>>(X, gm, bt, Y);
  };

  // ---- Block 1 (input x) ----
  gemm(x, W11, nullptr, B0, 256, 256);     // q
  gemm(x, W12, nullptr, B1, 256, 256);     // k
  gemm(x, W13, nullptr, B2, 256, 256);     // v
  attn(B0, B1, B2, B3);                    // o
  gemm(B3, W14, x, B0, 256, 256);          // x1 = relu(o@Wo)+x
  ln(B0, g1, b1, B1);                      // x1n
  gemm(B1, Wf11, nullptr, BF, 1024, 256);  // f = relu(x1n@Wf1)
  gemm(BF, Wf21, B1, B2, 256, 1024);       // x2 = relu(f@Wf2)+x1n
  ln(B2, g2, b2, B4);                      // block-1 out

  // ---- Block 2 (input B4) ----
  gemm(B4, W21, nullptr, B0, 256, 256);
  gemm(B4, W22, nullptr, B1, 256, 256);
  gemm(B4, W23, nullptr, B2, 256, 256);
  attn(B0, B1, B2, B3);
  gemm(B3, W24, B4, B0, 256, 256);
  ln(B0, g3, b3, B1);
  gemm(B1, Wf12, nullptr, BF, 1024, 256);
  gemm(BF, Wf22, B1, B2, 256, 1024);
  ln(B2, g4, b4, out);
}

// Round 3
// 657.893 us; speedup vs baseline: 3.9446x; 2.4603x over previous
//
#include <hip/hip_runtime.h>
#include <hip/hip_bf16.h>

// Encoder: B=4, S=2048, D=256, H=8, DK=32, DFF=1024, fp32 in/out.
// All projections are relu(x @ W^T). Two identical blocks.

#define MROWS 8192   // B*S
#define DMODEL 256
#define SEQ 2048
#define NHEAD 8
#define HDIM 32
#define LN_EPS 1e-5f

typedef float f32x4 __attribute__((ext_vector_type(4)));
typedef unsigned int u32x4 __attribute__((ext_vector_type(4)));

__device__ __forceinline__ unsigned short f2bf(float f) {
  unsigned int u = __float_as_uint(f);
  u += 0x7fffu + ((u >> 16) & 1u);  // round-to-nearest-even
  return (unsigned short)(u >> 16);
}

__device__ __forceinline__ f32x4 mfma_bf16(u32x4 a, u32x4 b, f32x4 c) {
  asm volatile("v_mfma_f32_16x16x32_bf16 %0, %1, %2, %0"
               : "+v"(c) : "v"(a), "v"(b));
  return c;
}

// ---------------- GEMM: C = relu(A @ W^T) (+ res) ----------------
__global__ __launch_bounds__(256) void gemm_relu_kernel(
    const float* __restrict__ A, const float* __restrict__ W,
    const float* __restrict__ res, float* __restrict__ C,
    int N, int K) {
  __shared__ float As[16][64];
  __shared__ float Ws[16][64];
  const int tid = threadIdx.x;
  const int m0 = blockIdx.y * 64;
  const int n0 = blockIdx.x * 64;
  const int tx = tid & 15, ty = tid >> 4;
  const int lrow = tid >> 2;
  const int lc4 = (tid & 3) * 4;

  float acc[4][4] = {};

  for (int k0 = 0; k0 < K; k0 += 16) {
    float4 a = *(const float4*)(A + (size_t)(m0 + lrow) * K + k0 + lc4);
    float4 w = *(const float4*)(W + (size_t)(n0 + lrow) * K + k0 + lc4);
    As[lc4 + 0][lrow] = a.x; As[lc4 + 1][lrow] = a.y;
    As[lc4 + 2][lrow] = a.z; As[lc4 + 3][lrow] = a.w;
    Ws[lc4 + 0][lrow] = w.x; Ws[lc4 + 1][lrow] = w.y;
    Ws[lc4 + 2][lrow] = w.z; Ws[lc4 + 3][lrow] = w.w;
    __syncthreads();
#pragma unroll
    for (int kk = 0; kk < 16; kk++) {
      float ar[4], wr[4];
#pragma unroll
      for (int i = 0; i < 4; i++) ar[i] = As[kk][ty * 4 + i];
#pragma unroll
      for (int j = 0; j < 4; j++) wr[j] = Ws[kk][tx * 4 + j];
#pragma unroll
      for (int i = 0; i < 4; i++)
#pragma unroll
        for (int j = 0; j < 4; j++) acc[i][j] += ar[i] * wr[j];
    }
    __syncthreads();
  }

#pragma unroll
  for (int i = 0; i < 4; i++) {
    const int m = m0 + ty * 4 + i;
    const int n = n0 + tx * 4;
    float4 v;
    v.x = fmaxf(acc[i][0], 0.f);
    v.y = fmaxf(acc[i][1], 0.f);
    v.z = fmaxf(acc[i][2], 0.f);
    v.w = fmaxf(acc[i][3], 0.f);
    if (res) {
      float4 r = *(const float4*)(res + (size_t)m * N + n);
      v.x += r.x; v.y += r.y; v.z += r.z; v.w += r.w;
    }
    *(float4*)(C + (size_t)m * N + n) = v;
  }
}

// ---------------- MFMA flash attention (bf16 compute, fp32 I/O) ----------
// Per block: 4 waves x 16 q rows. 32 keys per step (one 16x16x32 mfma pair).
// Swapped QK^T: S[key][q] so softmax stats are lane-local at col q=lane&15.
// PV computes O^T[d][q] (A = V^T staged transposed, B = P via LDS re-layout),
// so q stays lane-local for rescale/normalize.
__global__ __launch_bounds__(256) void attn_mfma_kernel(
    const float* __restrict__ Q, const float* __restrict__ K,
    const float* __restrict__ V, float* __restrict__ oP,
    float* __restrict__ mP, float* __restrict__ lP, int nkeys) {
  __shared__ alignas(16) unsigned short Ks[32][40];   // [key][dk], pad 40
  __shared__ alignas(16) unsigned short Vt[32][40];   // [d][key]
  __shared__ alignas(16) unsigned short Ps[4][16][40];  // per wave [q][key]

  const int tid = threadIdx.x;
  const int w = tid >> 6;
  const int lane = tid & 63;
  const int lq = lane & 15;   // q col (and d row for V frags)
  const int kg = lane >> 4;   // k-octet group
  const int bh = blockIdx.y, b = bh >> 3, h = bh & 7;
  const int p = blockIdx.z;
  const int q0 = blockIdx.x * 64 + w * 16;
  const size_t base = (size_t)b * SEQ * DMODEL + h * HDIM;

  // Q fragment (B operand): col q=lq, dk = kg*8 + 0..7
  union { unsigned short s[8]; u32x4 v; } qf;
  {
    const float* qp = Q + base + (size_t)(q0 + lq) * DMODEL + kg * 8;
    float4 a = *(const float4*)qp;
    float4 c = *(const float4*)(qp + 4);
    qf.s[0] = f2bf(a.x); qf.s[1] = f2bf(a.y);
    qf.s[2] = f2bf(a.z); qf.s[3] = f2bf(a.w);
    qf.s[4] = f2bf(c.x); qf.s[5] = f2bf(c.y);
    qf.s[6] = f2bf(c.z); qf.s[7] = f2bf(c.w);
  }

  f32x4 o0 = {0.f, 0.f, 0.f, 0.f};
  f32x4 o1 = {0.f, 0.f, 0.f, 0.f};
  float m_run = -1e30f, l_run = 0.f;
  const float C = 0.17677669529663687f * 1.4426950408889634f;  // scale*log2e

  const int sk = tid >> 3;        // staging key 0..31
  const int sd = (tid & 7) * 4;   // staging d 0,4,...,28

  const int kbeg = p * nkeys, kend = kbeg + nkeys;
  for (int kt = kbeg; kt < kend; kt += 32) {
    __syncthreads();
    {
      const float* kp = K + base + (size_t)(kt + sk) * DMODEL + sd;
      float4 kv = *(const float4*)kp;
      uint2 kw;
      kw.x = (unsigned)f2bf(kv.x) | ((unsigned)f2bf(kv.y) << 16);
      kw.y = (unsigned)f2bf(kv.z) | ((unsigned)f2bf(kv.w) << 16);
      *(uint2*)&Ks[sk][sd] = kw;
      const float* vp = V + base + (size_t)(kt + sk) * DMODEL + sd;
      float4 vv = *(const float4*)vp;
      Vt[sd + 0][sk] = f2bf(vv.x);
      Vt[sd + 1][sk] = f2bf(vv.y);
      Vt[sd + 2][sk] = f2bf(vv.z);
      Vt[sd + 3][sk] = f2bf(vv.w);
    }
    __syncthreads();

    // QK^T swapped: S[key][q]
    u32x4 k0 = *(const u32x4*)&Ks[lq][kg * 8];
    u32x4 k1 = *(const u32x4*)&Ks[16 + lq][kg * 8];
    f32x4 s0 = {0.f, 0.f, 0.f, 0.f};
    f32x4 s1 = {0.f, 0.f, 0.f, 0.f};
    s0 = mfma_bf16(k0, qf.v, s0);
    s1 = mfma_bf16(k1, qf.v, s1);

    float t[8];
#pragma unroll
    for (int r = 0; r < 4; r++) { t[r] = s0[r] * C; t[4 + r] = s1[r] * C; }
    float tmax = t[0];
#pragma unroll
    for (int i = 1; i < 8; i++) tmax = fmaxf(tmax, t[i]);
    tmax = fmaxf(tmax, __shfl_xor(tmax, 16));
    tmax = fmaxf(tmax, __shfl_xor(tmax, 32));

    const float mn = fmaxf(m_run, tmax);
    const float corr = exp2f(m_run - mn);
    m_run = mn;
    float pv[8];
    float ls = 0.f;
#pragma unroll
    for (int i = 0; i < 8; i++) { pv[i] = exp2f(t[i] - mn); ls += pv[i]; }
    ls += __shfl_xor(ls, 16);
    ls += __shfl_xor(ls, 32);
    l_run = l_run * corr + ls;
#pragma unroll
    for (int r = 0; r < 4; r++) { o0[r] *= corr; o1[r] *= corr; }

    // P -> bf16 -> per-wave LDS re-layout [q][key]
    uint2 pw0, pw1;
    pw0.x = (unsigned)f2bf(pv[0]) | ((unsigned)f2bf(pv[1]) << 16);
    pw0.y = (unsigned)f2bf(pv[2]) | ((unsigned)f2bf(pv[3]) << 16);
    pw1.x = (unsigned)f2bf(pv[4]) | ((unsigned)f2bf(pv[5]) << 16);
    pw1.y = (unsigned)f2bf(pv[6]) | ((unsigned)f2bf(pv[7]) << 16);
    *(uint2*)&Ps[w][lq][kg * 4] = pw0;
    *(uint2*)&Ps[w][lq][kg * 4 + 16] = pw1;

    u32x4 pf = *(const u32x4*)&Ps[w][lq][kg * 8];     // B: col q, keys kg*8..
    u32x4 v0 = *(const u32x4*)&Vt[lq][kg * 8];        // A: d=lq,   keys kg*8..
    u32x4 v1 = *(const u32x4*)&Vt[16 + lq][kg * 8];   // A: d=16+lq
    o0 = mfma_bf16(v0, pf, o0);
    o1 = mfma_bf16(v1, pf, o1);
  }

  // Epilogue: O^T[d][q]; lane holds q=lq, d = half*16 + kg*4 + r.
  const int qrow = q0 + lq;
  const size_t sidx = ((size_t)p * 32 + bh) * SEQ + qrow;
  if (kg == 0) { mP[sidx] = m_run; lP[sidx] = l_run; }
  float* op = oP + sidx * 32;
#pragma unroll
  for (int r = 0; r < 4; r++) {
    op[kg * 4 + r] = o0[r];         // unnormalized; combine divides
    op[16 + kg * 4 + r] = o1[r];
  }
}

// Merge NS partial flash states -> O[b, qrow, h*32..]
template <int NS>
__global__ __launch_bounds__(256) void attn_combine_kernel(
    const float* __restrict__ oP, const float* __restrict__ mP,
    const float* __restrict__ lP, float* __restrict__ O) {
  const int t = blockIdx.x * blockDim.x + threadIdx.x;  // 0..65535
  const int bh = t >> 11;
  const int qrow = t & 2047;
  const int b = bh >> 3, h = bh & 7;

  float mv[NS], lv[NS];
  float mmax = -1e30f;
#pragma unroll
  for (int pp = 0; pp < NS; pp++) {
    const size_t sidx = ((size_t)pp * 32 + bh) * SEQ + qrow;
    mv[pp] = mP[sidx];
    lv[pp] = lP[sidx];
    mmax = fmaxf(mmax, mv[pp]);
  }
  float lsum = 0.f;
  float w[NS];
#pragma unroll
  for (int pp = 0; pp < NS; pp++) {
    w[pp] = exp2f(mv[pp] - mmax);
    lsum += lv[pp] * w[pp];
  }
  const float inv = 1.f / lsum;

  float acc[32] = {};
#pragma unroll
  for (int pp = 0; pp < NS; pp++) {
    const float* op = oP + (((size_t)pp * 32 + bh) * SEQ + qrow) * 32;
#pragma unroll
    for (int i = 0; i < 8; i++) {
      float4 v = *(const float4*)(op + i * 4);
      acc[i * 4 + 0] += v.x * w[pp];
      acc[i * 4 + 1] += v.y * w[pp];
      acc[i * 4 + 2] += v.z * w[pp];
      acc[i * 4 + 3] += v.w * w[pp];
    }
  }
  float* outp = O + (size_t)b * SEQ * DMODEL + (size_t)qrow * DMODEL + h * HDIM;
#pragma unroll
  for (int i = 0; i < 8; i++) {
    float4 v;
    v.x = acc[i * 4 + 0] * inv; v.y = acc[i * 4 + 1] * inv;
    v.z = acc[i * 4 + 2] * inv; v.w = acc[i * 4 + 3] * inv;
    *(float4*)(outp + i * 4) = v;
  }
}

// ---------------- LayerNorm over last dim (256) ----------------
__global__ __launch_bounds__(256) void ln_kernel(
    const float* __restrict__ X, const float* __restrict__ g,
    const float* __restrict__ b, float* __restrict__ Y) {
  const int wid = (blockIdx.x * blockDim.x + threadIdx.x) >> 6;  // row
  const int lane = threadIdx.x & 63;
  const float* x = X + (size_t)wid * DMODEL;
  float4 v = *(const float4*)(x + lane * 4);
  float s = v.x + v.y + v.z + v.w;
  float s2 = v.x * v.x + v.y * v.y + v.z * v.z + v.w * v.w;
#pragma unroll
  for (int off = 32; off >= 1; off >>= 1) {
    s += __shfl_xor(s, off, 64);
    s2 += __shfl_xor(s2, off, 64);
  }
  const float mu = s * (1.f / DMODEL);
  const float var = s2 * (1.f / DMODEL) - mu * mu;
  const float inv = rsqrtf(var + LN_EPS);
  float4 gv = *(const float4*)(g + lane * 4);
  float4 bv = *(const float4*)(b + lane * 4);
  float4 out;
  out.x = (v.x - mu) * inv * gv.x + bv.x;
  out.y = (v.y - mu) * inv * gv.y + bv.y;
  out.z = (v.z - mu) * inv * gv.z + bv.z;
  out.w = (v.w - mu) * inv * gv.w + bv.w;
  *(float4*)(Y + (size_t)wid * DMODEL + lane * 4) = out;
}

extern "C" void kernel_launch(void* const* d_in, const int* in_sizes, int n_in,
                              void* d_out, int out_size, void* d_ws, size_t ws_size,
                              hipStream_t stream) {
  const float* x   = (const float*)d_in[0];
  const float* W11 = (const float*)d_in[1];
  const float* W12 = (const float*)d_in[2];
  const float* W13 = (const float*)d_in[3];
  const float* W14 = (const float*)d_in[4];
  const float* W21 = (const float*)d_in[5];
  const float* W22 = (const float*)d_in[6];
  const float* W23 = (const float*)d_in[7];
  const float* W24 = (const float*)d_in[8];
  const float* Wf11 = (const float*)d_in[9];
  const float* Wf21 = (const float*)d_in[10];
  const float* Wf12 = (const float*)d_in[11];
  const float* Wf22 = (const float*)d_in[12];
  const float* g1 = (const float*)d_in[13];
  const float* b1 = (const float*)d_in[14];
  const float* g2 = (const float*)d_in[15];
  const float* b2 = (const float*)d_in[16];
  const float* g3 = (const float*)d_in[17];
  const float* b3 = (const float*)d_in[18];
  const float* g4 = (const float*)d_in[19];
  const float* b4 = (const float*)d_in[20];

  float* out = (float*)d_out;
  float* ws = (float*)d_ws;
  const size_t NM = (size_t)MROWS * DMODEL;  // 2.10M floats
  float* B0 = ws;
  float* B1 = ws + NM;
  float* B2 = ws + 2 * NM;
  float* B3 = ws + 3 * NM;
  float* BF = ws + 4 * NM;  // 8192x1024 == 4*NM floats
  float* B4 = out;          // block-1 output lives in d_out temporarily

  const size_t ML = (size_t)32 * SEQ;  // 65536 per split
  int nsplit = 2;
  {
    size_t need = (8 * NM + (size_t)nsplit * 2 * ML) * sizeof(float);
    if (ws_size < need) nsplit = 1;
  }
  float* oP = BF;
  float* mP = BF + (size_t)nsplit * NM;
  float* lP = mP + (size_t)nsplit * ML;

  auto gemm = [&](const float* A, const float* W, const float* res, float* C,
                  int N, int K) {
    dim3 grid(N / 64, MROWS / 64);
    gemm_relu_kernel<<<grid, 256, 0, stream>>>(A, W, res, C, N, K);
  };
  auto attn = [&](const float* Q, const float* K, const float* V, float* O) {
    dim3 grid(SEQ / 64, 32, nsplit);
    attn_mfma_kernel<<<grid, 256, 0, stream>>>(Q, K, V, oP, mP, lP,
                                               SEQ / nsplit);
    if (nsplit == 2)
      attn_combine_kernel<2><<<65536 / 256, 256, 0, stream>>>(oP, mP, lP, O);
    else
      attn_combine_kernel<1><<<65536 / 256, 256, 0, stream>>>(oP, mP, lP, O);
  };
  auto ln = [&](const float* X, const float* gm, const float* bt, float* Y) {
    ln_kernel<<<MROWS / 4, 256, 0, stream>>>(X, gm, bt, Y);
  };

  // ---- Block 1 (input x) ----
  gemm(x, W11, nullptr, B0, 256, 256);     // q
  gemm(x, W12, nullptr, B1, 256, 256);     // k
  gemm(x, W13, nullptr, B2, 256, 256);     // v
  attn(B0, B1, B2, B3);                    // o
  gemm(B3, W14, x, B0, 256, 256);          // x1 = relu(o@Wo)+x
  ln(B0, g1, b1, B1);                      // x1n
  gemm(B1, Wf11, nullptr, BF, 1024, 256);  // f = relu(x1n@Wf1)
  gemm(BF, Wf21, B1, B2, 256, 1024);       // x2 = relu(f@Wf2)+x1n
  ln(B2, g2, b2, B4);                      // block-1 out

  // ---- Block 2 (input B4) ----
  gemm(B4, W21, nullptr, B0, 256, 256);
  gemm(B4, W22, nullptr, B1, 256, 256);
  gemm(B4, W23, nullptr, B2, 256, 256);
  attn(B0, B1, B2, B3);
  gemm(B3, W24, B4, B0, 256, 256);
  ln(B0, g3, b3, B1);
  gemm(B1, Wf12, nullptr, BF, 1024, 256);
  gemm(BF, Wf22, B1, B2, 256, 1024);
  ln(B2, g4, b4, out);
}

// Round 4
// 443.504 us; speedup vs baseline: 5.8514x; 1.4834x over previous
//
#include <hip/hip_runtime.h>
#include <hip/hip_bf16.h>

// Encoder: B=4, S=2048, D=256, H=8, DK=32, DFF=1024, fp32 in/out.
// All projections are relu(x @ W^T). Two identical blocks.

#define MROWS 8192   // B*S
#define DMODEL 256
#define SEQ 2048
#define NHEAD 8
#define HDIM 32
#define LN_EPS 1e-5f

typedef float f32x4 __attribute__((ext_vector_type(4)));
typedef unsigned int u32x4 __attribute__((ext_vector_type(4)));

__device__ __forceinline__ unsigned pk2(float lo, float hi) {
  union { __hip_bfloat162 h; unsigned u; } c;
  c.h = __float22bfloat162_rn(make_float2(lo, hi));
  return c.u;
}
__device__ __forceinline__ unsigned short bf1(float f) {
  union { __hip_bfloat16 h; unsigned short u; } c;
  c.h = __float2bfloat16(f);
  return c.u;
}

__device__ __forceinline__ f32x4 mfma_bf16(u32x4 a, u32x4 b, f32x4 c) {
  asm volatile("v_mfma_f32_16x16x32_bf16 %0, %1, %2, %0"
               : "+v"(c) : "v"(a), "v"(b));
  return c;
}

// ---------------- MFMA GEMM: C = relu(A @ W^T) (+ res) ----------------
// A: [M x K] fp32 row-major, W: [N x K] fp32 row-major, C/res: [M x N] fp32.
// Tile 128x64, 4 waves (2x2), each wave 64x32 (4x2 fragments of 16x16).
// BK=32 (one mfma K). fp32 -> bf16 conversion fused into LDS staging.
__global__ __launch_bounds__(256) void gemm_mfma_kernel(
    const float* __restrict__ A, const float* __restrict__ W,
    const float* __restrict__ res, float* __restrict__ C,
    int N, int K) {
  __shared__ alignas(16) unsigned short As[128][40];  // pad 40: 2-way banks
  __shared__ alignas(16) unsigned short Ws[64][40];
  const int tid = threadIdx.x;
  const int w = tid >> 6, lane = tid & 63;
  const int lq = lane & 15, kg = lane >> 4;
  const int wm = w >> 1, wn = w & 1;
  const int m0 = blockIdx.y * 128, n0 = blockIdx.x * 64;

  const int ar = tid >> 1, ac = (tid & 1) * 16;   // A stage: row, col16
  const int wrr = tid >> 2, wcc = (tid & 3) * 8;  // W stage: row, col8

  f32x4 acc[4][2] = {};

  for (int k0 = 0; k0 < K; k0 += 32) {
    const float* ap = A + (size_t)(m0 + ar) * K + k0 + ac;
    float4 a0 = *(const float4*)(ap);
    float4 a1 = *(const float4*)(ap + 4);
    float4 a2 = *(const float4*)(ap + 8);
    float4 a3 = *(const float4*)(ap + 12);
    const float* wp = W + (size_t)(n0 + wrr) * K + k0 + wcc;
    float4 w0 = *(const float4*)(wp);
    float4 w1 = *(const float4*)(wp + 4);
    __syncthreads();  // prev iter's ds_reads complete before overwrite
    uint4 pa0, pa1, pw;
    pa0.x = pk2(a0.x, a0.y); pa0.y = pk2(a0.z, a0.w);
    pa0.z = pk2(a1.x, a1.y); pa0.w = pk2(a1.z, a1.w);
    pa1.x = pk2(a2.x, a2.y); pa1.y = pk2(a2.z, a2.w);
    pa1.z = pk2(a3.x, a3.y); pa1.w = pk2(a3.z, a3.w);
    pw.x = pk2(w0.x, w0.y); pw.y = pk2(w0.z, w0.w);
    pw.z = pk2(w1.x, w1.y); pw.w = pk2(w1.z, w1.w);
    *(uint4*)&As[ar][ac] = pa0;
    *(uint4*)&As[ar][ac + 8] = pa1;
    *(uint4*)&Ws[wrr][wcc] = pw;
    __syncthreads();

    u32x4 b0 = *(const u32x4*)&Ws[wn * 32 + lq][kg * 8];
    u32x4 b1 = *(const u32x4*)&Ws[wn * 32 + 16 + lq][kg * 8];
#pragma unroll
    for (int mi = 0; mi < 4; mi++) {
      u32x4 af = *(const u32x4*)&As[wm * 64 + mi * 16 + lq][kg * 8];
      acc[mi][0] = mfma_bf16(af, b0, acc[mi][0]);
      acc[mi][1] = mfma_bf16(af, b1, acc[mi][1]);
    }
  }

  // Epilogue: D row = kg*4+r, col = lq within each 16x16 tile.
#pragma unroll
  for (int mi = 0; mi < 4; mi++) {
    const int m = m0 + wm * 64 + mi * 16 + kg * 4;
#pragma unroll
    for (int nj = 0; nj < 2; nj++) {
      const int n = n0 + wn * 32 + nj * 16 + lq;
#pragma unroll
      for (int r = 0; r < 4; r++) {
        float v = fmaxf(acc[mi][nj][r], 0.f);
        if (res) v += res[(size_t)(m + r) * N + n];
        C[(size_t)(m + r) * N + n] = v;
      }
    }
  }
}

// ---------------- MFMA flash attention (bf16 compute, fp32 I/O) ----------
__global__ __launch_bounds__(256) void attn_mfma_kernel(
    const float* __restrict__ Q, const float* __restrict__ K,
    const float* __restrict__ V, float* __restrict__ oP,
    float* __restrict__ mP, float* __restrict__ lP, int nkeys) {
  __shared__ alignas(16) unsigned short Ks[32][40];     // [key][dk]
  __shared__ alignas(16) unsigned short Vt[32][40];     // [d][key]
  __shared__ alignas(16) unsigned short Ps[4][16][40];  // per wave [q][key]

  const int tid = threadIdx.x;
  const int w = tid >> 6;
  const int lane = tid & 63;
  const int lq = lane & 15;
  const int kg = lane >> 4;
  const int bh = blockIdx.y, b = bh >> 3, h = bh & 7;
  const int p = blockIdx.z;
  const int q0 = blockIdx.x * 64 + w * 16;
  const size_t base = (size_t)b * SEQ * DMODEL + h * HDIM;

  union { unsigned short s[8]; u32x4 v; } qf;
  {
    const float* qp = Q + base + (size_t)(q0 + lq) * DMODEL + kg * 8;
    float4 a = *(const float4*)qp;
    float4 c = *(const float4*)(qp + 4);
    qf.v[0] = pk2(a.x, a.y); qf.v[1] = pk2(a.z, a.w);
    qf.v[2] = pk2(c.x, c.y); qf.v[3] = pk2(c.z, c.w);
  }

  f32x4 o0 = {0.f, 0.f, 0.f, 0.f};
  f32x4 o1 = {0.f, 0.f, 0.f, 0.f};
  float m_run = -1e30f, l_run = 0.f;
  const float C = 0.17677669529663687f * 1.4426950408889634f;  // scale*log2e

  const int sk = tid >> 3;
  const int sd = (tid & 7) * 4;

  const int kbeg = p * nkeys, kend = kbeg + nkeys;
  for (int kt = kbeg; kt < kend; kt += 32) {
    __syncthreads();
    {
      const float* kp = K + base + (size_t)(kt + sk) * DMODEL + sd;
      float4 kv = *(const float4*)kp;
      uint2 kw;
      kw.x = pk2(kv.x, kv.y);
      kw.y = pk2(kv.z, kv.w);
      *(uint2*)&Ks[sk][sd] = kw;
      const float* vp = V + base + (size_t)(kt + sk) * DMODEL + sd;
      float4 vv = *(const float4*)vp;
      Vt[sd + 0][sk] = bf1(vv.x);
      Vt[sd + 1][sk] = bf1(vv.y);
      Vt[sd + 2][sk] = bf1(vv.z);
      Vt[sd + 3][sk] = bf1(vv.w);
    }
    __syncthreads();

    u32x4 k0 = *(const u32x4*)&Ks[lq][kg * 8];
    u32x4 k1 = *(const u32x4*)&Ks[16 + lq][kg * 8];
    f32x4 s0 = {0.f, 0.f, 0.f, 0.f};
    f32x4 s1 = {0.f, 0.f, 0.f, 0.f};
    s0 = mfma_bf16(k0, qf.v, s0);
    s1 = mfma_bf16(k1, qf.v, s1);

    float t[8];
#pragma unroll
    for (int r = 0; r < 4; r++) { t[r] = s0[r] * C; t[4 + r] = s1[r] * C; }
    float tmax = t[0];
#pragma unroll
    for (int i = 1; i < 8; i++) tmax = fmaxf(tmax, t[i]);
    tmax = fmaxf(tmax, __shfl_xor(tmax, 16));
    tmax = fmaxf(tmax, __shfl_xor(tmax, 32));

    const float mn = fmaxf(m_run, tmax);
    const float corr = exp2f(m_run - mn);
    m_run = mn;
    float pv[8];
    float ls = 0.f;
#pragma unroll
    for (int i = 0; i < 8; i++) { pv[i] = exp2f(t[i] - mn); ls += pv[i]; }
    ls += __shfl_xor(ls, 16);
    ls += __shfl_xor(ls, 32);
    l_run = l_run * corr + ls;
#pragma unroll
    for (int r = 0; r < 4; r++) { o0[r] *= corr; o1[r] *= corr; }

    uint2 pw0, pw1;
    pw0.x = pk2(pv[0], pv[1]); pw0.y = pk2(pv[2], pv[3]);
    pw1.x = pk2(pv[4], pv[5]); pw1.y = pk2(pv[6], pv[7]);
    *(uint2*)&Ps[w][lq][kg * 4] = pw0;
    *(uint2*)&Ps[w][lq][kg * 4 + 16] = pw1;

    u32x4 pf = *(const u32x4*)&Ps[w][lq][kg * 8];
    u32x4 v0 = *(const u32x4*)&Vt[lq][kg * 8];
    u32x4 v1 = *(const u32x4*)&Vt[16 + lq][kg * 8];
    o0 = mfma_bf16(v0, pf, o0);
    o1 = mfma_bf16(v1, pf, o1);
  }

  const int qrow = q0 + lq;
  const size_t sidx = ((size_t)p * 32 + bh) * SEQ + qrow;
  if (kg == 0) { mP[sidx] = m_run; lP[sidx] = l_run; }
  float* op = oP + sidx * 32;
#pragma unroll
  for (int r = 0; r < 4; r++) {
    op[kg * 4 + r] = o0[r];
    op[16 + kg * 4 + r] = o1[r];
  }
}

// Merge NS partial flash states -> O[b, qrow, h*32..]
template <int NS>
__global__ __launch_bounds__(256) void attn_combine_kernel(
    const float* __restrict__ oP, const float* __restrict__ mP,
    const float* __restrict__ lP, float* __restrict__ O) {
  const int t = blockIdx.x * blockDim.x + threadIdx.x;
  const int bh = t >> 11;
  const int qrow = t & 2047;
  const int b = bh >> 3, h = bh & 7;

  float mv[NS], lv[NS];
  float mmax = -1e30f;
#pragma unroll
  for (int pp = 0; pp < NS; pp++) {
    const size_t sidx = ((size_t)pp * 32 + bh) * SEQ + qrow;
    mv[pp] = mP[sidx];
    lv[pp] = lP[sidx];
    mmax = fmaxf(mmax, mv[pp]);
  }
  float lsum = 0.f;
  float w[NS];
#pragma unroll
  for (int pp = 0; pp < NS; pp++) {
    w[pp] = exp2f(mv[pp] - mmax);
    lsum += lv[pp] * w[pp];
  }
  const float inv = 1.f / lsum;

  float acc[32] = {};
#pragma unroll
  for (int pp = 0; pp < NS; pp++) {
    const float* op = oP + (((size_t)pp * 32 + bh) * SEQ + qrow) * 32;
#pragma unroll
    for (int i = 0; i < 8; i++) {
      float4 v = *(const float4*)(op + i * 4);
      acc[i * 4 + 0] += v.x * w[pp];
      acc[i * 4 + 1] += v.y * w[pp];
      acc[i * 4 + 2] += v.z * w[pp];
      acc[i * 4 + 3] += v.w * w[pp];
    }
  }
  float* outp = O + (size_t)b * SEQ * DMODEL + (size_t)qrow * DMODEL + h * HDIM;
#pragma unroll
  for (int i = 0; i < 8; i++) {
    float4 v;
    v.x = acc[i * 4 + 0] * inv; v.y = acc[i * 4 + 1] * inv;
    v.z = acc[i * 4 + 2] * inv; v.w = acc[i * 4 + 3] * inv;
    *(float4*)(outp + i * 4) = v;
  }
}

// ---------------- LayerNorm over last dim (256) ----------------
__global__ __launch_bounds__(256) void ln_kernel(
    const float* __restrict__ X, const float* __restrict__ g,
    const float* __restrict__ b, float* __restrict__ Y) {
  const int wid = (blockIdx.x * blockDim.x + threadIdx.x) >> 6;
  const int lane = threadIdx.x & 63;
  const float* x = X + (size_t)wid * DMODEL;
  float4 v = *(const float4*)(x + lane * 4);
  float s = v.x + v.y + v.z + v.w;
  float s2 = v.x * v.x + v.y * v.y + v.z * v.z + v.w * v.w;
#pragma unroll
  for (int off = 32; off >= 1; off >>= 1) {
    s += __shfl_xor(s, off, 64);
    s2 += __shfl_xor(s2, off, 64);
  }
  const float mu = s * (1.f / DMODEL);
  const float var = s2 * (1.f / DMODEL) - mu * mu;
  const float inv = rsqrtf(var + LN_EPS);
  float4 gv = *(const float4*)(g + lane * 4);
  float4 bv = *(const float4*)(b + lane * 4);
  float4 out;
  out.x = (v.x - mu) * inv * gv.x + bv.x;
  out.y = (v.y - mu) * inv * gv.y + bv.y;
  out.z = (v.z - mu) * inv * gv.z + bv.z;
  out.w = (v.w - mu) * inv * gv.w + bv.w;
  *(float4*)(Y + (size_t)wid * DMODEL + lane * 4) = out;
}

extern "C" void kernel_launch(void* const* d_in, const int* in_sizes, int n_in,
                              void* d_out, int out_size, void* d_ws, size_t ws_size,
                              hipStream_t stream) {
  const float* x   = (const float*)d_in[0];
  const float* W11 = (const float*)d_in[1];
  const float* W12 = (const float*)d_in[2];
  const float* W13 = (const float*)d_in[3];
  const float* W14 = (const float*)d_in[4];
  const float* W21 = (const float*)d_in[5];
  const float* W22 = (const float*)d_in[6];
  const float* W23 = (const float*)d_in[7];
  const float* W24 = (const float*)d_in[8];
  const float* Wf11 = (const float*)d_in[9];
  const float* Wf21 = (const float*)d_in[10];
  const float* Wf12 = (const float*)d_in[11];
  const float* Wf22 = (const float*)d_in[12];
  const float* g1 = (const float*)d_in[13];
  const float* b1 = (const float*)d_in[14];
  const float* g2 = (const float*)d_in[15];
  const float* b2 = (const float*)d_in[16];
  const float* g3 = (const float*)d_in[17];
  const float* b3 = (const float*)d_in[18];
  const float* g4 = (const float*)d_in[19];
  const float* b4 = (const float*)d_in[20];

  float* out = (float*)d_out;
  float* ws = (float*)d_ws;
  const size_t NM = (size_t)MROWS * DMODEL;  // 2.10M floats
  float* B0 = ws;
  float* B1 = ws + NM;
  float* B2 = ws + 2 * NM;
  float* B3 = ws + 3 * NM;
  float* BF = ws + 4 * NM;  // 8192x1024 == 4*NM floats
  float* B4 = out;          // block-1 output lives in d_out temporarily

  const size_t ML = (size_t)32 * SEQ;  // 65536 per split
  int nsplit = 2;
  {
    size_t need = (8 * NM + (size_t)nsplit * 2 * ML) * sizeof(float);
    if (ws_size < need) nsplit = 1;
  }
  float* oP = BF;
  float* mP = BF + (size_t)nsplit * NM;
  float* lP = mP + (size_t)nsplit * ML;

  auto gemm = [&](const float* A, const float* W, const float* res, float* C,
                  int N, int K) {
    dim3 grid(N / 64, MROWS / 128);
    gemm_mfma_kernel<<<grid, 256, 0, stream>>>(A, W, res, C, N, K);
  };
  auto attn = [&](const float* Q, const float* K, const float* V, float* O) {
    dim3 grid(SEQ / 64, 32, nsplit);
    attn_mfma_kernel<<<grid, 256, 0, stream>>>(Q, K, V, oP, mP, lP,
                                               SEQ / nsplit);
    if (nsplit == 2)
      attn_combine_kernel<2><<<65536 / 256, 256, 0, stream>>>(oP, mP, lP, O);
    else
      attn_combine_kernel<1><<<65536 / 256, 256, 0, stream>>>(oP, mP, lP, O);
  };
  auto ln = [&](const float* X, const float* gm, const float* bt, float* Y) {
    ln_kernel<<<MROWS / 4, 256, 0, stream>>>(X, gm, bt, Y);
  };

  // ---- Block 1 (input x) ----
  gemm(x, W11, nullptr, B0, 256, 256);     // q
  gemm(x, W12, nullptr, B1, 256, 256);     // k
  gemm(x, W13, nullptr, B2, 256, 256);     // v
  attn(B0, B1, B2, B3);                    // o
  gemm(B3, W14, x, B0, 256, 256);          // x1 = relu(o@Wo)+x
  ln(B0, g1, b1, B1);                      // x1n
  gemm(B1, Wf11, nullptr, BF, 1024, 256);  // f = relu(x1n@Wf1)
  gemm(BF, Wf21, B1, B2, 256, 1024);       // x2 = relu(f@Wf2)+x1n
  ln(B2, g2, b2, B4);                      // block-1 out

  // ---- Block 2 (input B4) ----
  gemm(B4, W21, nullptr, B0, 256, 256);
  gemm(B4, W22, nullptr, B1, 256, 256);
  gemm(B4, W23, nullptr, B2, 256, 256);
  attn(B0, B1, B2, B3);
  gemm(B3, W24, B4, B0, 256, 256);
  ln(B0, g3, b3, B1);
  gemm(B1, Wf12, nullptr, BF, 1024, 256);
  gemm(BF, Wf22, B1, B2, 256, 1024);
  ln(B2, g4, b4, out);
}

// Round 5
// 344.460 us; speedup vs baseline: 7.5339x; 1.2875x over previous
//
#include <hip/hip_runtime.h>
#include <hip/hip_bf16.h>

// Encoder: B=4, S=2048, D=256, H=8, DK=32, DFF=1024, fp32 in/out.
// bf16 activation pipeline; fp32 residual stream; bf16 MFMA everywhere.

#define MROWS 8192   // B*S
#define DMODEL 256
#define SEQ 2048
#define LN_EPS 1e-5f

typedef float f32x4 __attribute__((ext_vector_type(4)));
typedef unsigned int u32x4 __attribute__((ext_vector_type(4)));

__device__ __forceinline__ unsigned pk2(float lo, float hi) {
  union { __hip_bfloat162 h; unsigned u; } c;
  c.h = __float22bfloat162_rn(make_float2(lo, hi));
  return c.u;
}
__device__ __forceinline__ unsigned short bf1(float f) {
  union { __hip_bfloat16 h; unsigned short u; } c;
  c.h = __float2bfloat16(f);
  return c.u;
}

__device__ __forceinline__ f32x4 mfma_bf16(u32x4 a, u32x4 b, f32x4 c) {
  asm volatile("v_mfma_f32_16x16x32_bf16 %0, %1, %2, %0"
               : "+v"(c) : "v"(a), "v"(b));
  return c;
}

__device__ __forceinline__ void gload_lds16(const void* g, void* l) {
  __builtin_amdgcn_global_load_lds(
      (const __attribute__((address_space(1))) void*)g,
      (__attribute__((address_space(3))) void*)l, 16, 0, 0);
}

// ---------------- fp32 -> bf16 batch convert ----------------
struct CvtArgs {
  const float* s[13];
  unsigned short* d[13];
  int n4[13];  // element count / 4
};
__global__ __launch_bounds__(256) void cvt_kernel(CvtArgs a) {
  const int y = blockIdx.y;
  const int n4 = a.n4[y];
  const float4* src = (const float4*)a.s[y];
  unsigned short* dst = a.d[y];
  for (int i = blockIdx.x * 256 + threadIdx.x; i < n4; i += 256 * 256) {
    float4 v = src[i];
    uint2 o;
    o.x = pk2(v.x, v.y);
    o.y = pk2(v.z, v.w);
    *(uint2*)(dst + (size_t)i * 4) = o;
  }
}

// ---------------- bf16 MFMA GEMM: relu(A @ W^T) (+res) ----------------
// A: [M x K] bf16, W: [N x K] bf16. Tile 128x64, BK=64, 4 waves (2x2),
// each wave 64x32 = 4x2 fragments. global_load_lds staging (linear LDS).
__global__ __launch_bounds__(256) void gemm_bf16_kernel(
    const unsigned short* __restrict__ A, const unsigned short* __restrict__ W,
    const float* __restrict__ res, float* __restrict__ outF,
    unsigned short* __restrict__ outB, int N, int K) {
  __shared__ alignas(16) unsigned short As[128][64];  // 16 KB
  __shared__ alignas(16) unsigned short Ws[64][64];   // 8 KB
  const int tid = threadIdx.x;
  const int w = tid >> 6, lane = tid & 63;
  const int lq = lane & 15, kg = lane >> 4;
  const int wm = w >> 1, wn = w & 1;
  const int m0 = blockIdx.y * 128, n0 = blockIdx.x * 64;
  const int r8 = lane >> 3;            // row within 8-row chunk
  const int c16 = (lane & 7) * 16;     // byte col within 128B row

  f32x4 acc[4][2] = {};

  for (int k0 = 0; k0 < K; k0 += 64) {
    __syncthreads();  // prev tile's ds_reads done before overwrite
#pragma unroll
    for (int i = 0; i < 4; i++) {          // A: 16 chunks of 8 rows
      const int chunk = w + i * 4;
      const int row = chunk * 8 + r8;
      const char* src = (const char*)A + ((size_t)(m0 + row) * K + k0) * 2 + c16;
      char* dst = (char*)&As[0][0] + chunk * 1024;
      gload_lds16(src, dst);
    }
#pragma unroll
    for (int i = 0; i < 2; i++) {          // W: 8 chunks of 8 rows
      const int chunk = w + i * 4;
      const int row = chunk * 8 + r8;
      const char* src = (const char*)W + ((size_t)(n0 + row) * K + k0) * 2 + c16;
      char* dst = (char*)&Ws[0][0] + chunk * 1024;
      gload_lds16(src, dst);
    }
    __syncthreads();  // compiler drains vmcnt before barrier

#pragma unroll
    for (int kk = 0; kk < 2; kk++) {
      u32x4 b0 = *(const u32x4*)&Ws[wn * 32 + lq][kk * 32 + kg * 8];
      u32x4 b1 = *(const u32x4*)&Ws[wn * 32 + 16 + lq][kk * 32 + kg * 8];
#pragma unroll
      for (int mi = 0; mi < 4; mi++) {
        u32x4 af = *(const u32x4*)&As[wm * 64 + mi * 16 + lq][kk * 32 + kg * 8];
        acc[mi][0] = mfma_bf16(af, b0, acc[mi][0]);
        acc[mi][1] = mfma_bf16(af, b1, acc[mi][1]);
      }
    }
  }

  // Epilogue: D row = kg*4+r, col = lq within each 16x16 tile.
#pragma unroll
  for (int mi = 0; mi < 4; mi++) {
    const int m = m0 + wm * 64 + mi * 16 + kg * 4;
#pragma unroll
    for (int nj = 0; nj < 2; nj++) {
      const int n = n0 + wn * 32 + nj * 16 + lq;
#pragma unroll
      for (int r = 0; r < 4; r++) {
        float v = fmaxf(acc[mi][nj][r], 0.f);
        if (res) v += res[(size_t)(m + r) * N + n];
        if (outF) outF[(size_t)(m + r) * N + n] = v;
        if (outB) outB[(size_t)(m + r) * N + n] = bf1(v);
      }
    }
  }
}

// ---------------- MFMA flash attention (bf16 in, fp32 partials out) ------
// Per block: 4 waves x 16 q rows, 32 keys/step. Swapped QK^T (stats
// lane-local at q=lane&15). PV computes O^T via transposed V in LDS.
__global__ __launch_bounds__(256) void attn_mfma_kernel(
    const unsigned short* __restrict__ Q, const unsigned short* __restrict__ K,
    const unsigned short* __restrict__ V, float* __restrict__ oP,
    float* __restrict__ mP, float* __restrict__ lP, int nkeys) {
  __shared__ alignas(16) unsigned short Ks[32][40];     // [key][dk]
  __shared__ alignas(16) unsigned short Vt[32][40];     // [d][key]
  __shared__ alignas(16) unsigned short Ps[4][16][40];  // per wave [q][key]

  const int tid = threadIdx.x;
  const int w = tid >> 6;
  const int lane = tid & 63;
  const int lq = lane & 15;
  const int kg = lane >> 4;
  const int bh = blockIdx.y, b = bh >> 3, h = bh & 7;
  const int p = blockIdx.z;
  const int q0 = blockIdx.x * 64 + w * 16;
  const size_t base = (size_t)b * SEQ * DMODEL + h * 32;

  u32x4 qf = *(const u32x4*)(Q + base + (size_t)(q0 + lq) * DMODEL + kg * 8);

  f32x4 o0 = {0.f, 0.f, 0.f, 0.f};
  f32x4 o1 = {0.f, 0.f, 0.f, 0.f};
  float m_run = -1e30f, l_run = 0.f;
  const float C = 0.17677669529663687f * 1.4426950408889634f;  // scale*log2e

  const int sk = tid >> 3;
  const int sd = (tid & 7) * 4;

  const int kbeg = p * nkeys, kend = kbeg + nkeys;
  for (int kt = kbeg; kt < kend; kt += 32) {
    __syncthreads();
    {
      uint2 kw = *(const uint2*)(K + base + (size_t)(kt + sk) * DMODEL + sd);
      *(uint2*)&Ks[sk][sd] = kw;
      uint2 vw = *(const uint2*)(V + base + (size_t)(kt + sk) * DMODEL + sd);
      Vt[sd + 0][sk] = (unsigned short)(vw.x & 0xffff);
      Vt[sd + 1][sk] = (unsigned short)(vw.x >> 16);
      Vt[sd + 2][sk] = (unsigned short)(vw.y & 0xffff);
      Vt[sd + 3][sk] = (unsigned short)(vw.y >> 16);
    }
    __syncthreads();

    u32x4 k0 = *(const u32x4*)&Ks[lq][kg * 8];
    u32x4 k1 = *(const u32x4*)&Ks[16 + lq][kg * 8];
    f32x4 s0 = {0.f, 0.f, 0.f, 0.f};
    f32x4 s1 = {0.f, 0.f, 0.f, 0.f};
    s0 = mfma_bf16(k0, qf, s0);
    s1 = mfma_bf16(k1, qf, s1);

    float t[8];
#pragma unroll
    for (int r = 0; r < 4; r++) { t[r] = s0[r] * C; t[4 + r] = s1[r] * C; }
    float tmax = t[0];
#pragma unroll
    for (int i = 1; i < 8; i++) tmax = fmaxf(tmax, t[i]);
    tmax = fmaxf(tmax, __shfl_xor(tmax, 16));
    tmax = fmaxf(tmax, __shfl_xor(tmax, 32));

    const float mn = fmaxf(m_run, tmax);
    const float corr = exp2f(m_run - mn);
    m_run = mn;
    float pv[8];
    float ls = 0.f;
#pragma unroll
    for (int i = 0; i < 8; i++) { pv[i] = exp2f(t[i] - mn); ls += pv[i]; }
    ls += __shfl_xor(ls, 16);
    ls += __shfl_xor(ls, 32);
    l_run = l_run * corr + ls;
#pragma unroll
    for (int r = 0; r < 4; r++) { o0[r] *= corr; o1[r] *= corr; }

    uint2 pw0, pw1;
    pw0.x = pk2(pv[0], pv[1]); pw0.y = pk2(pv[2], pv[3]);
    pw1.x = pk2(pv[4], pv[5]); pw1.y = pk2(pv[6], pv[7]);
    *(uint2*)&Ps[w][lq][kg * 4] = pw0;
    *(uint2*)&Ps[w][lq][kg * 4 + 16] = pw1;

    u32x4 pf = *(const u32x4*)&Ps[w][lq][kg * 8];
    u32x4 v0 = *(const u32x4*)&Vt[lq][kg * 8];
    u32x4 v1 = *(const u32x4*)&Vt[16 + lq][kg * 8];
    o0 = mfma_bf16(v0, pf, o0);
    o1 = mfma_bf16(v1, pf, o1);
  }

  const int qrow = q0 + lq;
  const size_t sidx = ((size_t)p * 32 + bh) * SEQ + qrow;
  if (kg == 0) { mP[sidx] = m_run; lP[sidx] = l_run; }
  float* op = oP + sidx * 32;
#pragma unroll
  for (int r = 0; r < 4; r++) {
    op[kg * 4 + r] = o0[r];
    op[16 + kg * 4 + r] = o1[r];
  }
}

// Merge NS partial flash states -> bf16 O[b, qrow, h*32..]
template <int NS>
__global__ __launch_bounds__(256) void attn_combine_kernel(
    const float* __restrict__ oP, const float* __restrict__ mP,
    const float* __restrict__ lP, unsigned short* __restrict__ O) {
  const int t = blockIdx.x * blockDim.x + threadIdx.x;
  const int bh = t >> 11;
  const int qrow = t & 2047;
  const int b = bh >> 3, h = bh & 7;

  float mv[NS], lv[NS];
  float mmax = -1e30f;
#pragma unroll
  for (int pp = 0; pp < NS; pp++) {
    const size_t sidx = ((size_t)pp * 32 + bh) * SEQ + qrow;
    mv[pp] = mP[sidx];
    lv[pp] = lP[sidx];
    mmax = fmaxf(mmax, mv[pp]);
  }
  float lsum = 0.f;
  float wgt[NS];
#pragma unroll
  for (int pp = 0; pp < NS; pp++) {
    wgt[pp] = exp2f(mv[pp] - mmax);
    lsum += lv[pp] * wgt[pp];
  }
  const float inv = 1.f / lsum;

  float acc[32] = {};
#pragma unroll
  for (int pp = 0; pp < NS; pp++) {
    const float* op = oP + (((size_t)pp * 32 + bh) * SEQ + qrow) * 32;
#pragma unroll
    for (int i = 0; i < 8; i++) {
      float4 v = *(const float4*)(op + i * 4);
      acc[i * 4 + 0] += v.x * wgt[pp];
      acc[i * 4 + 1] += v.y * wgt[pp];
      acc[i * 4 + 2] += v.z * wgt[pp];
      acc[i * 4 + 3] += v.w * wgt[pp];
    }
  }
  unsigned short* outp =
      O + (size_t)b * SEQ * DMODEL + (size_t)qrow * DMODEL + h * 32;
#pragma unroll
  for (int i = 0; i < 8; i++) {
    uint2 v;
    v.x = pk2(acc[i * 4 + 0] * inv, acc[i * 4 + 1] * inv);
    v.y = pk2(acc[i * 4 + 2] * inv, acc[i * 4 + 3] * inv);
    *(uint2*)(outp + i * 4) = v;
  }
}

// ---------------- LayerNorm (256) -> fp32 out (opt) + bf16 out (opt) ----
__global__ __launch_bounds__(256) void ln_kernel(
    const float* __restrict__ X, const float* __restrict__ g,
    const float* __restrict__ b, float* __restrict__ Y,
    unsigned short* __restrict__ Yb) {
  const int wid = (blockIdx.x * blockDim.x + threadIdx.x) >> 6;
  const int lane = threadIdx.x & 63;
  const float* x = X + (size_t)wid * DMODEL;
  float4 v = *(const float4*)(x + lane * 4);
  float s = v.x + v.y + v.z + v.w;
  float s2 = v.x * v.x + v.y * v.y + v.z * v.z + v.w * v.w;
#pragma unroll
  for (int off = 32; off >= 1; off >>= 1) {
    s += __shfl_xor(s, off, 64);
    s2 += __shfl_xor(s2, off, 64);
  }
  const float mu = s * (1.f / DMODEL);
  const float var = s2 * (1.f / DMODEL) - mu * mu;
  const float inv = rsqrtf(var + LN_EPS);
  float4 gv = *(const float4*)(g + lane * 4);
  float4 bv = *(const float4*)(b + lane * 4);
  float4 o;
  o.x = (v.x - mu) * inv * gv.x + bv.x;
  o.y = (v.y - mu) * inv * gv.y + bv.y;
  o.z = (v.z - mu) * inv * gv.z + bv.z;
  o.w = (v.w - mu) * inv * gv.w + bv.w;
  if (Y) *(float4*)(Y + (size_t)wid * DMODEL + lane * 4) = o;
  if (Yb) {
    uint2 p;
    p.x = pk2(o.x, o.y);
    p.y = pk2(o.z, o.w);
    *(uint2*)(Yb + (size_t)wid * DMODEL + lane * 4) = p;
  }
}

extern "C" void kernel_launch(void* const* d_in, const int* in_sizes, int n_in,
                              void* d_out, int out_size, void* d_ws, size_t ws_size,
                              hipStream_t stream) {
  const float* x = (const float*)d_in[0];
  const float* g1 = (const float*)d_in[13];
  const float* b1 = (const float*)d_in[14];
  const float* g2 = (const float*)d_in[15];
  const float* b2 = (const float*)d_in[16];
  const float* g3 = (const float*)d_in[17];
  const float* b3 = (const float*)d_in[18];
  const float* g4 = (const float*)d_in[19];
  const float* b4 = (const float*)d_in[20];

  float* out = (float*)d_out;
  float* ws = (float*)d_ws;
  const size_t NM = (size_t)MROWS * DMODEL;  // 2.10M elements
  const size_t ML = (size_t)32 * SEQ;        // 65536 per split

  // fp32: residual stream scratch
  float* F0 = ws;
  float* F1 = ws + NM;
  // union region (2NM floats == 8NM bytes): oP fp32 | fb bf16 (8192x1024)
  char* U = (char*)(ws + 2 * NM);
  float* oP = (float*)U;
  unsigned short* fb = (unsigned short*)U;
  float* mP = ws + 4 * NM;
  float* lP = mP + 2 * ML;
  // bf16 activations
  unsigned short* xb = (unsigned short*)(lP + 2 * ML);
  unsigned short* qb = xb + NM;
  unsigned short* kb = qb + NM;
  unsigned short* vb = kb + NM;
  unsigned short* ob = vb + NM;
  unsigned short* nb = ob + NM;
  // bf16 weights: 8 x 65536 then 4 x 262144
  unsigned short* wb = nb + NM;
  unsigned short* wp[12];
  {
    unsigned short* c = wb;
    for (int i = 0; i < 8; i++) { wp[i] = c; c += 65536; }
    for (int i = 8; i < 12; i++) { wp[i] = c; c += 262144; }
  }

  // ---- convert x + weights to bf16 (one launch) ----
  {
    CvtArgs a;
    a.s[0] = x; a.d[0] = xb; a.n4[0] = (int)(NM / 4);
    for (int i = 0; i < 12; i++) {
      a.s[i + 1] = (const float*)d_in[i + 1];
      a.d[i + 1] = wp[i];
      a.n4[i + 1] = (i < 8) ? 65536 / 4 : 262144 / 4;
    }
    cvt_kernel<<<dim3(256, 13), 256, 0, stream>>>(a);
  }

  auto gemm = [&](const unsigned short* A, const unsigned short* W,
                  const float* res, float* oF, unsigned short* oB,
                  int N, int K) {
    gemm_bf16_kernel<<<dim3(N / 64, MROWS / 128), 256, 0, stream>>>(
        A, W, res, oF, oB, N, K);
  };
  auto attn = [&](const unsigned short* Q, const unsigned short* K,
                  const unsigned short* V, unsigned short* O) {
    attn_mfma_kernel<<<dim3(SEQ / 64, 32, 2), 256, 0, stream>>>(
        Q, K, V, oP, mP, lP, SEQ / 2);
    attn_combine_kernel<2><<<65536 / 256, 256, 0, stream>>>(oP, mP, lP, O);
  };
  auto ln = [&](const float* X, const float* gm, const float* bt, float* Y,
                unsigned short* Yb) {
    ln_kernel<<<MROWS / 4, 256, 0, stream>>>(X, gm, bt, Y, Yb);
  };

  // ---- Block 1 ----
  gemm(xb, wp[0], nullptr, nullptr, qb, 256, 256);   // q
  gemm(xb, wp[1], nullptr, nullptr, kb, 256, 256);   // k
  gemm(xb, wp[2], nullptr, nullptr, vb, 256, 256);   // v
  attn(qb, kb, vb, ob);                              // o (bf16)
  gemm(ob, wp[3], x, F0, nullptr, 256, 256);         // x1 = relu+x (fp32)
  ln(F0, g1, b1, F1, nb);                            // x1n (fp32+bf16)
  gemm(nb, wp[8], nullptr, nullptr, fb, 1024, 256);  // f (bf16)
  gemm(fb, wp[9], F1, F0, nullptr, 256, 1024);       // x2 = relu+x1n (fp32)
  ln(F0, g2, b2, F1, xb);                            // block1 out (fp32+bf16)

  // ---- Block 2 ----
  gemm(xb, wp[4], nullptr, nullptr, qb, 256, 256);
  gemm(xb, wp[5], nullptr, nullptr, kb, 256, 256);
  gemm(xb, wp[6], nullptr, nullptr, vb, 256, 256);
  attn(qb, kb, vb, ob);
  gemm(ob, wp[7], F1, F0, nullptr, 256, 256);        // x1' (F1 = block1 out)
  ln(F0, g3, b3, F1, nb);
  gemm(nb, wp[10], nullptr, nullptr, fb, 1024, 256);
  gemm(fb, wp[11], F1, F0, nullptr, 256, 1024);
  ln(F0, g4, b4, out, nullptr);
}

// Round 6
// 321.844 us; speedup vs baseline: 8.0633x; 1.0703x over previous
//
#include <hip/hip_runtime.h>
#include <hip/hip_bf16.h>

// Encoder: B=4, S=2048, D=256, H=8, DK=32, DFF=1024, fp32 in/out.
// bf16 activation pipeline; fp32 residual stream; bf16 MFMA everywhere.

#define MROWS 8192   // B*S
#define DMODEL 256
#define SEQ 2048
#define LN_EPS 1e-5f

typedef float f32x4 __attribute__((ext_vector_type(4)));
typedef unsigned int u32x4 __attribute__((ext_vector_type(4)));

__device__ __forceinline__ unsigned pk2(float lo, float hi) {
  union { __hip_bfloat162 h; unsigned u; } c;
  c.h = __float22bfloat162_rn(make_float2(lo, hi));
  return c.u;
}
__device__ __forceinline__ unsigned short bf1(float f) {
  union { __hip_bfloat16 h; unsigned short u; } c;
  c.h = __float2bfloat16(f);
  return c.u;
}

__device__ __forceinline__ f32x4 mfma_bf16(u32x4 a, u32x4 b, f32x4 c) {
  asm volatile("v_mfma_f32_16x16x32_bf16 %0, %1, %2, %0"
               : "+v"(c) : "v"(a), "v"(b));
  return c;
}

__device__ __forceinline__ void gload_lds16(const void* g, void* l) {
  __builtin_amdgcn_global_load_lds(
      (const __attribute__((address_space(1))) void*)g,
      (__attribute__((address_space(3))) void*)l, 16, 0, 0);
}

// ---------------- fp32 -> bf16 batch convert ----------------
struct CvtArgs {
  const float* s[13];
  unsigned short* d[13];
  int n4[13];  // element count / 4
};
__global__ __launch_bounds__(256) void cvt_kernel(CvtArgs a) {
  const int y = blockIdx.y;
  const int n4 = a.n4[y];
  const float4* src = (const float4*)a.s[y];
  unsigned short* dst = a.d[y];
  for (int i = blockIdx.x * 256 + threadIdx.x; i < n4; i += 256 * 256) {
    float4 v = src[i];
    uint2 o;
    o.x = pk2(v.x, v.y);
    o.y = pk2(v.z, v.w);
    *(uint2*)(dst + (size_t)i * 4) = o;
  }
}

// ---------------- bf16 MFMA GEMM: relu(A @ W^T) (+res) ----------------
// A: [M x K] bf16, W: [N x K] bf16. Tile 128x64, BK=64, 4 waves (2x2),
// each wave 64x32 = 4x2 fragments. global_load_lds staging (linear LDS).
// Outputs (each optional): fp32 C, bf16 C, bf16 V^T ([b*8+h][d][s]).
__global__ __launch_bounds__(256) void gemm_bf16_kernel(
    const unsigned short* __restrict__ A, const unsigned short* __restrict__ W,
    const float* __restrict__ res, float* __restrict__ outF,
    unsigned short* __restrict__ outB, unsigned short* __restrict__ outVT,
    int N, int K) {
  __shared__ alignas(16) unsigned short As[128][64];  // 16 KB
  __shared__ alignas(16) unsigned short Ws[64][64];   // 8 KB
  const int tid = threadIdx.x;
  const int w = tid >> 6, lane = tid & 63;
  const int lq = lane & 15, kg = lane >> 4;
  const int wm = w >> 1, wn = w & 1;
  const int m0 = blockIdx.y * 128, n0 = blockIdx.x * 64;
  const int r8 = lane >> 3;            // row within 8-row chunk
  const int c16 = (lane & 7) * 16;     // byte col within 128B row

  f32x4 acc[4][2] = {};

  for (int k0 = 0; k0 < K; k0 += 64) {
    __syncthreads();  // prev tile's ds_reads done before overwrite
#pragma unroll
    for (int i = 0; i < 4; i++) {          // A: 16 chunks of 8 rows
      const int chunk = w + i * 4;
      const int row = chunk * 8 + r8;
      const char* src = (const char*)A + ((size_t)(m0 + row) * K + k0) * 2 + c16;
      char* dst = (char*)&As[0][0] + chunk * 1024;
      gload_lds16(src, dst);
    }
#pragma unroll
    for (int i = 0; i < 2; i++) {          // W: 8 chunks of 8 rows
      const int chunk = w + i * 4;
      const int row = chunk * 8 + r8;
      const char* src = (const char*)W + ((size_t)(n0 + row) * K + k0) * 2 + c16;
      char* dst = (char*)&Ws[0][0] + chunk * 1024;
      gload_lds16(src, dst);
    }
    __syncthreads();  // compiler drains vmcnt before barrier

#pragma unroll
    for (int kk = 0; kk < 2; kk++) {
      u32x4 b0 = *(const u32x4*)&Ws[wn * 32 + lq][kk * 32 + kg * 8];
      u32x4 b1 = *(const u32x4*)&Ws[wn * 32 + 16 + lq][kk * 32 + kg * 8];
#pragma unroll
      for (int mi = 0; mi < 4; mi++) {
        u32x4 af = *(const u32x4*)&As[wm * 64 + mi * 16 + lq][kk * 32 + kg * 8];
        acc[mi][0] = mfma_bf16(af, b0, acc[mi][0]);
        acc[mi][1] = mfma_bf16(af, b1, acc[mi][1]);
      }
    }
  }

  // Epilogue: D row = kg*4+r, col = lq within each 16x16 tile.
  if (res || outF || outB) {
#pragma unroll
    for (int mi = 0; mi < 4; mi++) {
      const int m = m0 + wm * 64 + mi * 16 + kg * 4;
#pragma unroll
      for (int nj = 0; nj < 2; nj++) {
        const int n = n0 + wn * 32 + nj * 16 + lq;
#pragma unroll
        for (int r = 0; r < 4; r++) {
          float v = fmaxf(acc[mi][nj][r], 0.f);
          if (res) v += res[(size_t)(m + r) * N + n];
          if (outF) outF[(size_t)(m + r) * N + n] = v;
          if (outB) outB[(size_t)(m + r) * N + n] = bf1(v);
        }
      }
    }
  }
  if (outVT) {  // V^T: [b*8+h][d 0..31][s 0..2047], 4 s-consecutive per store
#pragma unroll
    for (int mi = 0; mi < 4; mi++) {
      const int mb = m0 + wm * 64 + mi * 16 + kg * 4;
      const int bq = mb >> 11, s0 = mb & 2047;
#pragma unroll
      for (int nj = 0; nj < 2; nj++) {
        const int n = n0 + wn * 32 + nj * 16 + lq;
        const int hh = n >> 5, dd = n & 31;
        uint2 pv;
        pv.x = pk2(fmaxf(acc[mi][nj][0], 0.f), fmaxf(acc[mi][nj][1], 0.f));
        pv.y = pk2(fmaxf(acc[mi][nj][2], 0.f), fmaxf(acc[mi][nj][3], 0.f));
        *(uint2*)(outVT + ((size_t)(bq * 8 + hh) * 32 + dd) * 2048 + s0) = pv;
      }
    }
  }
}

// ---------------- MFMA flash attention (bf16 in, fp32 partials out) ------
// Per block: 4 waves x 16 q rows, 64 keys/step. Swapped QK^T (stats
// lane-local at q=lane&15). PV computes O^T via pre-transposed V (global).
__global__ __launch_bounds__(256) void attn_mfma_kernel(
    const unsigned short* __restrict__ Q, const unsigned short* __restrict__ K,
    const unsigned short* __restrict__ VT, float* __restrict__ oP,
    float* __restrict__ mP, float* __restrict__ lP, int nkeys) {
  __shared__ alignas(16) unsigned short Ks[64][40];     // [key][dk]
  __shared__ alignas(16) unsigned short Vt[32][72];     // [d][key]
  __shared__ alignas(16) unsigned short Ps[4][16][72];  // per wave [q][key]

  const int tid = threadIdx.x;
  const int w = tid >> 6;
  const int lane = tid & 63;
  const int lq = lane & 15;
  const int kg = lane >> 4;
  const int bh = blockIdx.y, b = bh >> 3, h = bh & 7;
  const int p = blockIdx.z;
  const int q0 = blockIdx.x * 64 + w * 16;
  const size_t base = (size_t)b * SEQ * DMODEL + h * 32;

  u32x4 qf = *(const u32x4*)(Q + base + (size_t)(q0 + lq) * DMODEL + kg * 8);

  f32x4 oA = {0.f, 0.f, 0.f, 0.f};   // d = kg*4+r (0..15)
  f32x4 oB = {0.f, 0.f, 0.f, 0.f};   // d = 16+kg*4+r
  float m_run = -1e30f, l_run = 0.f;
  const float C = 0.17677669529663687f * 1.4426950408889634f;  // scale*log2e

  const int krow = tid >> 2, kc = (tid & 3) * 8;   // K stage: 64 x 32
  const int vd = tid >> 3, vc = (tid & 7) * 8;     // V stage: 32 x 64
  const unsigned short* vtb = VT + (size_t)bh * 32 * 2048;

  const int kbeg = p * nkeys, kend = kbeg + nkeys;
  for (int kt = kbeg; kt < kend; kt += 64) {
    __syncthreads();
    *(uint4*)&Ks[krow][kc] =
        *(const uint4*)(K + base + (size_t)(kt + krow) * DMODEL + kc);
    *(uint4*)&Vt[vd][vc] =
        *(const uint4*)(vtb + (size_t)vd * 2048 + kt + vc);
    __syncthreads();

    // QK^T swapped: 4 mfma, keys s4*16 + kg*4 + r at col q=lq
    f32x4 sc[4];
#pragma unroll
    for (int s4 = 0; s4 < 4; s4++) {
      u32x4 ka = *(const u32x4*)&Ks[s4 * 16 + lq][kg * 8];
      f32x4 z = {0.f, 0.f, 0.f, 0.f};
      sc[s4] = mfma_bf16(ka, qf, z);
    }

    float t[16];
#pragma unroll
    for (int s4 = 0; s4 < 4; s4++)
#pragma unroll
      for (int r = 0; r < 4; r++) t[s4 * 4 + r] = sc[s4][r] * C;

    float m8[8], m4[4];
#pragma unroll
    for (int i = 0; i < 8; i++) m8[i] = fmaxf(t[2 * i], t[2 * i + 1]);
#pragma unroll
    for (int i = 0; i < 4; i++) m4[i] = fmaxf(m8[2 * i], m8[2 * i + 1]);
    float tmax = fmaxf(fmaxf(m4[0], m4[1]), fmaxf(m4[2], m4[3]));
    tmax = fmaxf(tmax, __shfl_xor(tmax, 16));
    tmax = fmaxf(tmax, __shfl_xor(tmax, 32));

    const float mn = fmaxf(m_run, tmax);
    const float corr = exp2f(m_run - mn);
    m_run = mn;

    float pe[16];
#pragma unroll
    for (int i = 0; i < 16; i++) pe[i] = exp2f(t[i] - mn);
    float s8[8], s4v[4];
#pragma unroll
    for (int i = 0; i < 8; i++) s8[i] = pe[2 * i] + pe[2 * i + 1];
#pragma unroll
    for (int i = 0; i < 4; i++) s4v[i] = s8[2 * i] + s8[2 * i + 1];
    float ls = (s4v[0] + s4v[1]) + (s4v[2] + s4v[3]);
    ls += __shfl_xor(ls, 16);
    ls += __shfl_xor(ls, 32);
    l_run = l_run * corr + ls;
#pragma unroll
    for (int r = 0; r < 4; r++) { oA[r] *= corr; oB[r] *= corr; }

    // P -> bf16 -> per-wave LDS [q][key]
#pragma unroll
    for (int s4 = 0; s4 < 4; s4++) {
      uint2 pw;
      pw.x = pk2(pe[s4 * 4 + 0], pe[s4 * 4 + 1]);
      pw.y = pk2(pe[s4 * 4 + 2], pe[s4 * 4 + 3]);
      *(uint2*)&Ps[w][lq][s4 * 16 + kg * 4] = pw;
    }

    u32x4 pf0 = *(const u32x4*)&Ps[w][lq][kg * 8];
    u32x4 pf1 = *(const u32x4*)&Ps[w][lq][32 + kg * 8];
    u32x4 va00 = *(const u32x4*)&Vt[lq][kg * 8];
    u32x4 va01 = *(const u32x4*)&Vt[lq][32 + kg * 8];
    u32x4 va10 = *(const u32x4*)&Vt[16 + lq][kg * 8];
    u32x4 va11 = *(const u32x4*)&Vt[16 + lq][32 + kg * 8];
    oA = mfma_bf16(va00, pf0, oA);
    oA = mfma_bf16(va01, pf1, oA);
    oB = mfma_bf16(va10, pf0, oB);
    oB = mfma_bf16(va11, pf1, oB);
  }

  const int qrow = q0 + lq;
  const size_t sidx = ((size_t)p * 32 + bh) * SEQ + qrow;
  if (kg == 0) { mP[sidx] = m_run; lP[sidx] = l_run; }
  float* op = oP + sidx * 32;
#pragma unroll
  for (int r = 0; r < 4; r++) {
    op[kg * 4 + r] = oA[r];
    op[16 + kg * 4 + r] = oB[r];
  }
}

// Merge NS partial flash states -> bf16 O[b, qrow, h*32..]
template <int NS>
__global__ __launch_bounds__(256) void attn_combine_kernel(
    const float* __restrict__ oP, const float* __restrict__ mP,
    const float* __restrict__ lP, unsigned short* __restrict__ O) {
  const int t = blockIdx.x * blockDim.x + threadIdx.x;
  const int bh = t >> 11;
  const int qrow = t & 2047;
  const int b = bh >> 3, h = bh & 7;

  float mv[NS], lv[NS];
  float mmax = -1e30f;
#pragma unroll
  for (int pp = 0; pp < NS; pp++) {
    const size_t sidx = ((size_t)pp * 32 + bh) * SEQ + qrow;
    mv[pp] = mP[sidx];
    lv[pp] = lP[sidx];
    mmax = fmaxf(mmax, mv[pp]);
  }
  float lsum = 0.f;
  float wgt[NS];
#pragma unroll
  for (int pp = 0; pp < NS; pp++) {
    wgt[pp] = exp2f(mv[pp] - mmax);
    lsum += lv[pp] * wgt[pp];
  }
  const float inv = 1.f / lsum;

  float acc[32] = {};
#pragma unroll
  for (int pp = 0; pp < NS; pp++) {
    const float* op = oP + (((size_t)pp * 32 + bh) * SEQ + qrow) * 32;
#pragma unroll
    for (int i = 0; i < 8; i++) {
      float4 v = *(const float4*)(op + i * 4);
      acc[i * 4 + 0] += v.x * wgt[pp];
      acc[i * 4 + 1] += v.y * wgt[pp];
      acc[i * 4 + 2] += v.z * wgt[pp];
      acc[i * 4 + 3] += v.w * wgt[pp];
    }
  }
  unsigned short* outp =
      O + (size_t)b * SEQ * DMODEL + (size_t)qrow * DMODEL + h * 32;
#pragma unroll
  for (int i = 0; i < 8; i++) {
    uint2 v;
    v.x = pk2(acc[i * 4 + 0] * inv, acc[i * 4 + 1] * inv);
    v.y = pk2(acc[i * 4 + 2] * inv, acc[i * 4 + 3] * inv);
    *(uint2*)(outp + i * 4) = v;
  }
}

// ---------------- LayerNorm (256) -> fp32 out (opt) + bf16 out (opt) ----
__global__ __launch_bounds__(256) void ln_kernel(
    const float* __restrict__ X, const float* __restrict__ g,
    const float* __restrict__ b, float* __restrict__ Y,
    unsigned short* __restrict__ Yb) {
  const int wid = (blockIdx.x * blockDim.x + threadIdx.x) >> 6;
  const int lane = threadIdx.x & 63;
  const float* x = X + (size_t)wid * DMODEL;
  float4 v = *(const float4*)(x + lane * 4);
  float s = v.x + v.y + v.z + v.w;
  float s2 = v.x * v.x + v.y * v.y + v.z * v.z + v.w * v.w;
#pragma unroll
  for (int off = 32; off >= 1; off >>= 1) {
    s += __shfl_xor(s, off, 64);
    s2 += __shfl_xor(s2, off, 64);
  }
  const float mu = s * (1.f / DMODEL);
  const float var = s2 * (1.f / DMODEL) - mu * mu;
  const float inv = rsqrtf(var + LN_EPS);
  float4 gv = *(const float4*)(g + lane * 4);
  float4 bv = *(const float4*)(b + lane * 4);
  float4 o;
  o.x = (v.x - mu) * inv * gv.x + bv.x;
  o.y = (v.y - mu) * inv * gv.y + bv.y;
  o.z = (v.z - mu) * inv * gv.z + bv.z;
  o.w = (v.w - mu) * inv * gv.w + bv.w;
  if (Y) *(float4*)(Y + (size_t)wid * DMODEL + lane * 4) = o;
  if (Yb) {
    uint2 p;
    p.x = pk2(o.x, o.y);
    p.y = pk2(o.z, o.w);
    *(uint2*)(Yb + (size_t)wid * DMODEL + lane * 4) = p;
  }
}

extern "C" void kernel_launch(void* const* d_in, const int* in_sizes, int n_in,
                              void* d_out, int out_size, void* d_ws, size_t ws_size,
                              hipStream_t stream) {
  const float* x = (const float*)d_in[0];
  const float* g1 = (const float*)d_in[13];
  const float* b1 = (const float*)d_in[14];
  const float* g2 = (const float*)d_in[15];
  const float* b2 = (const float*)d_in[16];
  const float* g3 = (const float*)d_in[17];
  const float* b3 = (const float*)d_in[18];
  const float* g4 = (const float*)d_in[19];
  const float* b4 = (const float*)d_in[20];

  float* out = (float*)d_out;
  float* ws = (float*)d_ws;
  const size_t NM = (size_t)MROWS * DMODEL;  // 2.10M elements
  const size_t ML = (size_t)32 * SEQ;        // 65536 per split

  // fp32: residual stream scratch
  float* F0 = ws;
  float* F1 = ws + NM;
  // union region (2NM floats == 8NM bytes): oP fp32 | fb bf16 (8192x1024)
  char* U = (char*)(ws + 2 * NM);
  float* oP = (float*)U;
  unsigned short* fb = (unsigned short*)U;
  float* mP = ws + 4 * NM;
  float* lP = mP + 2 * ML;
  // bf16 activations
  unsigned short* xb = (unsigned short*)(lP + 2 * ML);
  unsigned short* qb = xb + NM;
  unsigned short* kb = qb + NM;
  unsigned short* ob = kb + NM;
  unsigned short* nb = ob + NM;
  // bf16 weights: 8 x 65536 then 4 x 262144
  unsigned short* wb = nb + NM;
  unsigned short* wp[12];
  {
    unsigned short* c = wb;
    for (int i = 0; i < 8; i++) { wp[i] = c; c += 65536; }
    for (int i = 8; i < 12; i++) { wp[i] = c; c += 262144; }
  }
  // V^T [b*8+h][32][2048] bf16 (4 MB) aliases F0 (dead during V-gemm+attn)
  unsigned short* vt = (unsigned short*)F0;

  // ---- convert x + weights to bf16 (one launch) ----
  {
    CvtArgs a;
    a.s[0] = x; a.d[0] = xb; a.n4[0] = (int)(NM / 4);
    for (int i = 0; i < 12; i++) {
      a.s[i + 1] = (const float*)d_in[i + 1];
      a.d[i + 1] = wp[i];
      a.n4[i + 1] = (i < 8) ? 65536 / 4 : 262144 / 4;
    }
    cvt_kernel<<<dim3(256, 13), 256, 0, stream>>>(a);
  }

  auto gemm = [&](const unsigned short* A, const unsigned short* W,
                  const float* res, float* oF, unsigned short* oB,
                  unsigned short* oVT, int N, int K) {
    gemm_bf16_kernel<<<dim3(N / 64, MROWS / 128), 256, 0, stream>>>(
        A, W, res, oF, oB, oVT, N, K);
  };
  auto attn = [&](const unsigned short* Q, const unsigned short* K,
                  const unsigned short* VT, unsigned short* O) {
    attn_mfma_kernel<<<dim3(SEQ / 64, 32, 2), 256, 0, stream>>>(
        Q, K, VT, oP, mP, lP, SEQ / 2);
    attn_combine_kernel<2><<<65536 / 256, 256, 0, stream>>>(oP, mP, lP, O);
  };
  auto ln = [&](const float* X, const float* gm, const float* bt, float* Y,
                unsigned short* Yb) {
    ln_kernel<<<MROWS / 4, 256, 0, stream>>>(X, gm, bt, Y, Yb);
  };

  // ---- Block 1 ----
  gemm(xb, wp[0], nullptr, nullptr, qb, nullptr, 256, 256);   // q
  gemm(xb, wp[1], nullptr, nullptr, kb, nullptr, 256, 256);   // k
  gemm(xb, wp[2], nullptr, nullptr, nullptr, vt, 256, 256);   // v -> V^T
  attn(qb, kb, vt, ob);                                       // o (bf16)
  gemm(ob, wp[3], x, F0, nullptr, nullptr, 256, 256);         // x1 (fp32)
  ln(F0, g1, b1, F1, nb);                                     // x1n
  gemm(nb, wp[8], nullptr, nullptr, fb, nullptr, 1024, 256);  // f (bf16)
  gemm(fb, wp[9], F1, F0, nullptr, nullptr, 256, 1024);       // x2 (fp32)
  ln(F0, g2, b2, F1, xb);                                     // block1 out

  // ---- Block 2 ----
  gemm(xb, wp[4], nullptr, nullptr, qb, nullptr, 256, 256);
  gemm(xb, wp[5], nullptr, nullptr, kb, nullptr, 256, 256);
  gemm(xb, wp[6], nullptr, nullptr, nullptr, vt, 256, 256);
  attn(qb, kb, vt, ob);
  gemm(ob, wp[7], F1, F0, nullptr, nullptr, 256, 256);        // x1'
  ln(F0, g3, b3, F1, nb);
  gemm(nb, wp[10], nullptr, nullptr, fb, nullptr, 1024, 256);
  gemm(fb, wp[11], F1, F0, nullptr, nullptr, 256, 1024);
  ln(F0, g4, b4, out, nullptr);
}

// Round 7
// 296.227 us; speedup vs baseline: 8.7606x; 1.0865x over previous
//
#include <hip/hip_runtime.h>
#include <hip/hip_bf16.h>

// Encoder: B=4, S=2048, D=256, H=8, DK=32, DFF=1024, fp32 in/out.
// bf16 pipeline, swizzled-LDS MFMA GEMM + flash attention.

#define MROWS 8192   // B*S
#define DMODEL 256
#define SEQ 2048
#define LN_EPS 1e-5f

typedef float f32x4 __attribute__((ext_vector_type(4)));
typedef unsigned int u32x4 __attribute__((ext_vector_type(4)));

__device__ __forceinline__ unsigned pk2(float lo, float hi) {
  union { __hip_bfloat162 h; unsigned u; } c;
  c.h = __float22bfloat162_rn(make_float2(lo, hi));
  return c.u;
}
__device__ __forceinline__ unsigned short bf1(float f) {
  union { __hip_bfloat16 h; unsigned short u; } c;
  c.h = __float2bfloat16(f);
  return c.u;
}

__device__ __forceinline__ f32x4 mfma_bf16(u32x4 a, u32x4 b, f32x4 c) {
  asm volatile("v_mfma_f32_16x16x32_bf16 %0, %1, %2, %0"
               : "+v"(c) : "v"(a), "v"(b));
  return c;
}

__device__ __forceinline__ void gload_lds16(const void* g, void* l) {
  __builtin_amdgcn_global_load_lds(
      (const __attribute__((address_space(1))) void*)g,
      (__attribute__((address_space(3))) void*)l, 16, 0, 0);
}

// ---------------- fp32 -> bf16 batch convert ----------------
struct CvtArgs {
  const float* s[13];
  unsigned short* d[13];
  int n4[13];
};
__global__ __launch_bounds__(256) void cvt_kernel(CvtArgs a) {
  const int y = blockIdx.y;
  const int n4 = a.n4[y];
  const float4* src = (const float4*)a.s[y];
  unsigned short* dst = a.d[y];
  for (int i = blockIdx.x * 256 + threadIdx.x; i < n4; i += 256 * 256) {
    float4 v = src[i];
    uint2 o;
    o.x = pk2(v.x, v.y);
    o.y = pk2(v.z, v.w);
    *(uint2*)(dst + (size_t)i * 4) = o;
  }
}

// ---------------- bf16 MFMA GEMM: relu(A @ W^T) (+res) ----------------
// 512 threads, 8 waves (4m x 2n), block tile 128x64, wave tile 32x32,
// BK=64. LDS via global_load_lds with source-swizzle slot^=(row&7);
// reads use matching XOR -> 2-way banks (free).
__global__ __launch_bounds__(512) void gemm_bf16_kernel(
    const unsigned short* __restrict__ A, const unsigned short* __restrict__ W,
    const float* __restrict__ res, float* __restrict__ outF,
    unsigned short* __restrict__ outB, unsigned short* __restrict__ outVT,
    float bscale, int N, int K) {
  __shared__ alignas(16) unsigned short As[128 * 64];  // [row][8 slots of 8]
  __shared__ alignas(16) unsigned short Ws[64 * 64];
  const int tid = threadIdx.x;
  const int w = tid >> 6, lane = tid & 63;
  const int lq = lane & 15, kg = lane >> 4;
  const int wm = w >> 1, wn = w & 1;
  const int m0 = blockIdx.y * 128, n0 = blockIdx.x * 64;

  // staging: chunk = 1024B = 8 rows x 128B; lane covers (row=l>>3, slot=l&7)
  const int srow = lane >> 3;
  const int sg = (lane & 7) ^ srow;  // swizzled source slot

  f32x4 acc[2][2] = {};

  for (int k0 = 0; k0 < K; k0 += 64) {
    __syncthreads();
    // A: 16 chunks, wave stages w and w+8
#pragma unroll
    for (int i = 0; i < 2; i++) {
      const int c = w + i * 8;
      const int row = c * 8 + srow;
      gload_lds16(A + (size_t)(m0 + row) * K + k0 + sg * 8,
                  (char*)As + c * 1024);
    }
    {  // W: 8 chunks
      const int row = w * 8 + srow;
      gload_lds16(W + (size_t)(n0 + row) * K + k0 + sg * 8,
                  (char*)Ws + w * 1024);
    }
    __syncthreads();

#pragma unroll
    for (int kk = 0; kk < 2; kk++) {
      const int sl0 = ((kk * 4 + kg) ^ (lq & 7)) * 8;
      u32x4 b0 = *(const u32x4*)&Ws[((wn * 32 + lq) << 6) + sl0];
      u32x4 b1 = *(const u32x4*)&Ws[((wn * 32 + 16 + lq) << 6) + sl0];
      u32x4 a0 = *(const u32x4*)&As[((wm * 32 + lq) << 6) + sl0];
      u32x4 a1 = *(const u32x4*)&As[((wm * 32 + 16 + lq) << 6) + sl0];
      __builtin_amdgcn_s_setprio(1);
      acc[0][0] = mfma_bf16(a0, b0, acc[0][0]);
      acc[0][1] = mfma_bf16(a0, b1, acc[0][1]);
      acc[1][0] = mfma_bf16(a1, b0, acc[1][0]);
      acc[1][1] = mfma_bf16(a1, b1, acc[1][1]);
      __builtin_amdgcn_s_setprio(0);
    }
  }

  // Epilogue: D row = kg*4+r, col = lq per 16x16 frag.
  if (res || outF || outB) {
#pragma unroll
    for (int mi = 0; mi < 2; mi++) {
      const int m = m0 + wm * 32 + mi * 16 + kg * 4;
#pragma unroll
      for (int nj = 0; nj < 2; nj++) {
        const int n = n0 + wn * 32 + nj * 16 + lq;
#pragma unroll
        for (int r = 0; r < 4; r++) {
          float v = fmaxf(acc[mi][nj][r], 0.f);
          if (res) v += res[(size_t)(m + r) * N + n];
          if (outF) outF[(size_t)(m + r) * N + n] = v;
          if (outB) outB[(size_t)(m + r) * N + n] = bf1(v * bscale);
        }
      }
    }
  }
  if (outVT) {  // V^T: [b*8+h][d 0..31][s 0..2047]
#pragma unroll
    for (int mi = 0; mi < 2; mi++) {
      const int mb = m0 + wm * 32 + mi * 16 + kg * 4;
      const int bq = mb >> 11, s0 = mb & 2047;
#pragma unroll
      for (int nj = 0; nj < 2; nj++) {
        const int n = n0 + wn * 32 + nj * 16 + lq;
        const int hh = n >> 5, dd = n & 31;
        uint2 pv;
        pv.x = pk2(fmaxf(acc[mi][nj][0], 0.f), fmaxf(acc[mi][nj][1], 0.f));
        pv.y = pk2(fmaxf(acc[mi][nj][2], 0.f), fmaxf(acc[mi][nj][3], 0.f));
        *(uint2*)(outVT + ((size_t)(bq * 8 + hh) * 32 + dd) * 2048 + s0) = pv;
      }
    }
  }
}

// ---------------- MFMA flash attention (bf16 in, fp32 partials out) ------
// 4 waves x 16 q rows, 64 keys/step. Q pre-scaled by scale*log2e.
// K tile swizzle slot^=(row>>1)&3; V tile slot^=(d&7); staged via
// global_load_lds (linear dest) with pre-swizzled global source.
__global__ __launch_bounds__(256) void attn_mfma_kernel(
    const unsigned short* __restrict__ Q, const unsigned short* __restrict__ K,
    const unsigned short* __restrict__ VT, float* __restrict__ oP,
    float* __restrict__ mP, float* __restrict__ lP, int nkeys) {
  __shared__ alignas(16) unsigned short Ks[64 * 32];   // [key][4 slots of 8]
  __shared__ alignas(16) unsigned short Vt[32 * 64];   // [d][8 slots of 8]
  __shared__ alignas(16) unsigned short Ps[4][16][72];

  const int tid = threadIdx.x;
  const int w = tid >> 6;
  const int lane = tid & 63;
  const int lq = lane & 15;
  const int kg = lane >> 4;
  const int bh = blockIdx.y, b = bh >> 3, h = bh & 7;
  const int p = blockIdx.z;
  const int q0 = blockIdx.x * 64 + w * 16;
  const size_t base = (size_t)b * SEQ * DMODEL + h * 32;

  u32x4 qf = *(const u32x4*)(Q + base + (size_t)(q0 + lq) * DMODEL + kg * 8);

  f32x4 oA = {0.f, 0.f, 0.f, 0.f};
  f32x4 oB = {0.f, 0.f, 0.f, 0.f};
  float m_run = -1e30f, l_run = 0.f;

  // staging source-swizzles (row-local parts fold to lane-only forms)
  const int kg4 = (lane & 3) ^ ((lane >> 3) & 3);  // K: slot^(row>>1)&3
  const int vg8 = (lane & 7) ^ (lane >> 3);        // V: slot^(d&7)
  const unsigned short* vtb = VT + (size_t)bh * 32 * 2048;

  const int kslot = ((lq >> 1) & 3);  // K read swizzle base
  const int vslot = (lq & 7);         // V read swizzle base

  const int kbeg = p * nkeys, kend = kbeg + nkeys;
  for (int kt = kbeg; kt < kend; kt += 64) {
    __syncthreads();
    {  // K: 4 chunks (16 rows ea), wave w stages chunk w
      const int row = w * 16 + (lane >> 2);
      gload_lds16(K + base + (size_t)(kt + row) * DMODEL + kg4 * 8,
                  (char*)Ks + w * 1024);
      // V: 4 chunks (8 d-rows ea)
      const int d = w * 8 + (lane >> 3);
      gload_lds16(vtb + (size_t)d * 2048 + kt + vg8 * 8,
                  (char*)Vt + w * 1024);
    }
    __syncthreads();

    // QK^T swapped: keys s4*16+kg*4+r at col q=lq
    f32x4 sc[4];
    __builtin_amdgcn_s_setprio(1);
#pragma unroll
    for (int s4 = 0; s4 < 4; s4++) {
      u32x4 ka = *(const u32x4*)&Ks[((s4 * 16 + lq) << 5) + ((kg ^ kslot) << 3)];
      f32x4 z = {0.f, 0.f, 0.f, 0.f};
      sc[s4] = mfma_bf16(ka, qf, z);
    }
    __builtin_amdgcn_s_setprio(0);

    float m8[8], m4[4];
#pragma unroll
    for (int i = 0; i < 8; i++) m8[i] = fmaxf(sc[i >> 1][(i & 1) * 2], sc[i >> 1][(i & 1) * 2 + 1]);
#pragma unroll
    for (int i = 0; i < 4; i++) m4[i] = fmaxf(m8[2 * i], m8[2 * i + 1]);
    float tmax = fmaxf(fmaxf(m4[0], m4[1]), fmaxf(m4[2], m4[3]));
    tmax = fmaxf(tmax, __shfl_xor(tmax, 16));
    tmax = fmaxf(tmax, __shfl_xor(tmax, 32));

    if (!__all(tmax <= m_run)) {  // exact defer-max: rescale only if needed
      const float mn = fmaxf(m_run, tmax);
      const float corr = exp2f(m_run - mn);
      m_run = mn;
      l_run *= corr;
#pragma unroll
      for (int r = 0; r < 4; r++) { oA[r] *= corr; oB[r] *= corr; }
    }

    float pe[16];
#pragma unroll
    for (int s4 = 0; s4 < 4; s4++)
#pragma unroll
      for (int r = 0; r < 4; r++) pe[s4 * 4 + r] = exp2f(sc[s4][r] - m_run);
    float s8[8], s4v[4];
#pragma unroll
    for (int i = 0; i < 8; i++) s8[i] = pe[2 * i] + pe[2 * i + 1];
#pragma unroll
    for (int i = 0; i < 4; i++) s4v[i] = s8[2 * i] + s8[2 * i + 1];
    float ls = (s4v[0] + s4v[1]) + (s4v[2] + s4v[3]);
    ls += __shfl_xor(ls, 16);
    ls += __shfl_xor(ls, 32);
    l_run += ls;

#pragma unroll
    for (int s4 = 0; s4 < 4; s4++) {
      uint2 pw;
      pw.x = pk2(pe[s4 * 4 + 0], pe[s4 * 4 + 1]);
      pw.y = pk2(pe[s4 * 4 + 2], pe[s4 * 4 + 3]);
      *(uint2*)&Ps[w][lq][s4 * 16 + kg * 4] = pw;
    }

    u32x4 pf0 = *(const u32x4*)&Ps[w][lq][kg * 8];
    u32x4 pf1 = *(const u32x4*)&Ps[w][lq][32 + kg * 8];
    u32x4 va00 = *(const u32x4*)&Vt[(lq << 6) + ((kg ^ vslot) << 3)];
    u32x4 va01 = *(const u32x4*)&Vt[(lq << 6) + (((4 | kg) ^ vslot) << 3)];
    u32x4 va10 = *(const u32x4*)&Vt[((16 + lq) << 6) + ((kg ^ vslot) << 3)];
    u32x4 va11 = *(const u32x4*)&Vt[((16 + lq) << 6) + (((4 | kg) ^ vslot) << 3)];
    __builtin_amdgcn_s_setprio(1);
    oA = mfma_bf16(va00, pf0, oA);
    oA = mfma_bf16(va01, pf1, oA);
    oB = mfma_bf16(va10, pf0, oB);
    oB = mfma_bf16(va11, pf1, oB);
    __builtin_amdgcn_s_setprio(0);
  }

  const int qrow = q0 + lq;
  const size_t sidx = ((size_t)p * 32 + bh) * SEQ + qrow;
  if (kg == 0) { mP[sidx] = m_run; lP[sidx] = l_run; }
  float* op = oP + sidx * 32;
#pragma unroll
  for (int r = 0; r < 4; r++) {
    op[kg * 4 + r] = oA[r];
    op[16 + kg * 4 + r] = oB[r];
  }
}

// Merge NS partial flash states -> bf16 O
template <int NS>
__global__ __launch_bounds__(256) void attn_combine_kernel(
    const float* __restrict__ oP, const float* __restrict__ mP,
    const float* __restrict__ lP, unsigned short* __restrict__ O) {
  const int t = blockIdx.x * blockDim.x + threadIdx.x;
  const int bh = t >> 11;
  const int qrow = t & 2047;
  const int b = bh >> 3, h = bh & 7;

  float mv[NS], lv[NS];
  float mmax = -1e30f;
#pragma unroll
  for (int pp = 0; pp < NS; pp++) {
    const size_t sidx = ((size_t)pp * 32 + bh) * SEQ + qrow;
    mv[pp] = mP[sidx];
    lv[pp] = lP[sidx];
    mmax = fmaxf(mmax, mv[pp]);
  }
  float lsum = 0.f;
  float wgt[NS];
#pragma unroll
  for (int pp = 0; pp < NS; pp++) {
    wgt[pp] = exp2f(mv[pp] - mmax);
    lsum += lv[pp] * wgt[pp];
  }
  const float inv = 1.f / lsum;

  float acc[32] = {};
#pragma unroll
  for (int pp = 0; pp < NS; pp++) {
    const float* op = oP + (((size_t)pp * 32 + bh) * SEQ + qrow) * 32;
#pragma unroll
    for (int i = 0; i < 8; i++) {
      float4 v = *(const float4*)(op + i * 4);
      acc[i * 4 + 0] += v.x * wgt[pp];
      acc[i * 4 + 1] += v.y * wgt[pp];
      acc[i * 4 + 2] += v.z * wgt[pp];
      acc[i * 4 + 3] += v.w * wgt[pp];
    }
  }
  unsigned short* outp =
      O + (size_t)b * SEQ * DMODEL + (size_t)qrow * DMODEL + h * 32;
#pragma unroll
  for (int i = 0; i < 8; i++) {
    uint2 v;
    v.x = pk2(acc[i * 4 + 0] * inv, acc[i * 4 + 1] * inv);
    v.y = pk2(acc[i * 4 + 2] * inv, acc[i * 4 + 3] * inv);
    *(uint2*)(outp + i * 4) = v;
  }
}

// ---------------- LayerNorm (256) ----------------
__global__ __launch_bounds__(256) void ln_kernel(
    const float* __restrict__ X, const float* __restrict__ g,
    const float* __restrict__ b, float* __restrict__ Y,
    unsigned short* __restrict__ Yb) {
  const int wid = (blockIdx.x * blockDim.x + threadIdx.x) >> 6;
  const int lane = threadIdx.x & 63;
  const float* x = X + (size_t)wid * DMODEL;
  float4 v = *(const float4*)(x + lane * 4);
  float s = v.x + v.y + v.z + v.w;
  float s2 = v.x * v.x + v.y * v.y + v.z * v.z + v.w * v.w;
#pragma unroll
  for (int off = 32; off >= 1; off >>= 1) {
    s += __shfl_xor(s, off, 64);
    s2 += __shfl_xor(s2, off, 64);
  }
  const float mu = s * (1.f / DMODEL);
  const float var = s2 * (1.f / DMODEL) - mu * mu;
  const float inv = rsqrtf(var + LN_EPS);
  float4 gv = *(const float4*)(g + lane * 4);
  float4 bv = *(const float4*)(b + lane * 4);
  float4 o;
  o.x = (v.x - mu) * inv * gv.x + bv.x;
  o.y = (v.y - mu) * inv * gv.y + bv.y;
  o.z = (v.z - mu) * inv * gv.z + bv.z;
  o.w = (v.w - mu) * inv * gv.w + bv.w;
  if (Y) *(float4*)(Y + (size_t)wid * DMODEL + lane * 4) = o;
  if (Yb) {
    uint2 p;
    p.x = pk2(o.x, o.y);
    p.y = pk2(o.z, o.w);
    *(uint2*)(Yb + (size_t)wid * DMODEL + lane * 4) = p;
  }
}

extern "C" void kernel_launch(void* const* d_in, const int* in_sizes, int n_in,
                              void* d_out, int out_size, void* d_ws, size_t ws_size,
                              hipStream_t stream) {
  const float* x = (const float*)d_in[0];
  const float* g1 = (const float*)d_in[13];
  const float* b1 = (const float*)d_in[14];
  const float* g2 = (const float*)d_in[15];
  const float* b2 = (const float*)d_in[16];
  const float* g3 = (const float*)d_in[17];
  const float* b3 = (const float*)d_in[18];
  const float* g4 = (const float*)d_in[19];
  const float* b4 = (const float*)d_in[20];

  float* out = (float*)d_out;
  float* ws = (float*)d_ws;
  const size_t NM = (size_t)MROWS * DMODEL;
  const size_t ML = (size_t)32 * SEQ;
  const float QSCALE = 0.17677669529663687f * 1.4426950408889634f;

  float* F0 = ws;
  float* F1 = ws + NM;
  char* U = (char*)(ws + 2 * NM);
  float* oP = (float*)U;
  unsigned short* fb = (unsigned short*)U;
  float* mP = ws + 4 * NM;
  float* lP = mP + 2 * ML;
  unsigned short* xb = (unsigned short*)(lP + 2 * ML);
  unsigned short* qb = xb + NM;
  unsigned short* kb = qb + NM;
  unsigned short* ob = kb + NM;
  unsigned short* nb = ob + NM;
  unsigned short* wb = nb + NM;
  unsigned short* wp[12];
  {
    unsigned short* c = wb;
    for (int i = 0; i < 8; i++) { wp[i] = c; c += 65536; }
    for (int i = 8; i < 12; i++) { wp[i] = c; c += 262144; }
  }
  unsigned short* vt = (unsigned short*)F0;  // aliases F0 (dead then)

  {
    CvtArgs a;
    a.s[0] = x; a.d[0] = xb; a.n4[0] = (int)(NM / 4);
    for (int i = 0; i < 12; i++) {
      a.s[i + 1] = (const float*)d_in[i + 1];
      a.d[i + 1] = wp[i];
      a.n4[i + 1] = (i < 8) ? 65536 / 4 : 262144 / 4;
    }
    cvt_kernel<<<dim3(256, 13), 256, 0, stream>>>(a);
  }

  auto gemm = [&](const unsigned short* A, const unsigned short* W,
                  const float* res, float* oF, unsigned short* oB,
                  unsigned short* oVT, float bs, int N, int K) {
    gemm_bf16_kernel<<<dim3(N / 64, MROWS / 128), 512, 0, stream>>>(
        A, W, res, oF, oB, oVT, bs, N, K);
  };
  auto attn = [&](const unsigned short* Q, const unsigned short* K,
                  const unsigned short* VT, unsigned short* O) {
    attn_mfma_kernel<<<dim3(SEQ / 64, 32, 2), 256, 0, stream>>>(
        Q, K, VT, oP, mP, lP, SEQ / 2);
    attn_combine_kernel<2><<<65536 / 256, 256, 0, stream>>>(oP, mP, lP, O);
  };
  auto ln = [&](const float* X, const float* gm, const float* bt, float* Y,
                unsigned short* Yb) {
    ln_kernel<<<MROWS / 4, 256, 0, stream>>>(X, gm, bt, Y, Yb);
  };

  // ---- Block 1 ----
  gemm(xb, wp[0], nullptr, nullptr, qb, nullptr, QSCALE, 256, 256);  // q
  gemm(xb, wp[1], nullptr, nullptr, kb, nullptr, 1.f, 256, 256);     // k
  gemm(xb, wp[2], nullptr, nullptr, nullptr, vt, 1.f, 256, 256);     // v->V^T
  attn(qb, kb, vt, ob);
  gemm(ob, wp[3], x, F0, nullptr, nullptr, 1.f, 256, 256);           // x1
  ln(F0, g1, b1, F1, nb);
  gemm(nb, wp[8], nullptr, nullptr, fb, nullptr, 1.f, 1024, 256);    // f
  gemm(fb, wp[9], F1, F0, nullptr, nullptr, 1.f, 256, 1024);         // x2
  ln(F0, g2, b2, F1, xb);

  // ---- Block 2 ----
  gemm(xb, wp[4], nullptr, nullptr, qb, nullptr, QSCALE, 256, 256);
  gemm(xb, wp[5], nullptr, nullptr, kb, nullptr, 1.f, 256, 256);
  gemm(xb, wp[6], nullptr, nullptr, nullptr, vt, 1.f, 256, 256);
  attn(qb, kb, vt, ob);
  gemm(ob, wp[7], F1, F0, nullptr, nullptr, 1.f, 256, 256);
  ln(F0, g3, b3, F1, nb);
  gemm(nb, wp[10], nullptr, nullptr, fb, nullptr, 1.f, 1024, 256);
  gemm(fb, wp[11], F1, F0, nullptr, nullptr, 1.f, 256, 1024);
  ln(F0, g4, b4, out, nullptr);
}

// Round 8
// 246.615 us; speedup vs baseline: 10.5230x; 1.2012x over previous
//
#include <hip/hip_runtime.h>
#include <hip/hip_bf16.h>

// Encoder: B=4, S=2048, D=256, H=8, DK=32, DFF=1024, fp32 in/out.
// bf16 pipeline. Fixed-base softmax (scores>=0 via ReLU'd q,k), l via
// ones-MFMA, double-buffered GEMM + attention, fused QKV projection.

#define MROWS 8192   // B*S
#define DMODEL 256
#define SEQ 2048
#define LN_EPS 1e-5f

typedef float f32x4 __attribute__((ext_vector_type(4)));
typedef unsigned int u32x4 __attribute__((ext_vector_type(4)));

__device__ __forceinline__ unsigned pk2(float lo, float hi) {
  union { __hip_bfloat162 h; unsigned u; } c;
  c.h = __float22bfloat162_rn(make_float2(lo, hi));
  return c.u;
}
__device__ __forceinline__ unsigned short bf1(float f) {
  union { __hip_bfloat16 h; unsigned short u; } c;
  c.h = __float2bfloat16(f);
  return c.u;
}

__device__ __forceinline__ f32x4 mfma_bf16(u32x4 a, u32x4 b, f32x4 c) {
  asm volatile("v_mfma_f32_16x16x32_bf16 %0, %1, %2, %0"
               : "+v"(c) : "v"(a), "v"(b));
  return c;
}

__device__ __forceinline__ void gload_lds16(const void* g, void* l) {
  __builtin_amdgcn_global_load_lds(
      (const __attribute__((address_space(1))) void*)g,
      (__attribute__((address_space(3))) void*)l, 16, 0, 0);
}

// ---------------- fp32 -> bf16 batch convert ----------------
struct CvtArgs {
  const float* s[13];
  unsigned short* d[13];
  int n4[13];
};
__global__ __launch_bounds__(256) void cvt_kernel(CvtArgs a) {
  const int y = blockIdx.y;
  const int n4 = a.n4[y];
  const float4* src = (const float4*)a.s[y];
  unsigned short* dst = a.d[y];
  for (int i = blockIdx.x * 256 + threadIdx.x; i < n4; i += 256 * 256) {
    float4 v = src[i];
    uint2 o;
    o.x = pk2(v.x, v.y);
    o.y = pk2(v.z, v.w);
    *(uint2*)(dst + (size_t)i * 4) = o;
  }
}

// ---------------- bf16 MFMA GEMM: relu(A @ W^T) (+res) ----------------
// 256 threads, 4 waves (2x2), block 64x64, wave 32x32, BK=64, double-buffer
// LDS staged via global_load_lds (linear dest, pre-swizzled source).
// Fused-QKV epilogue: n<256 -> outB (bscale), [256,512) -> outB2,
// >=512 -> outVT (V^T [b*8+h][d][s]). XCD-swizzled 1D grid.
__global__ __launch_bounds__(256) void gemm_bf16_kernel(
    const unsigned short* __restrict__ A, const unsigned short* __restrict__ W,
    const float* __restrict__ res, float* __restrict__ outF,
    unsigned short* __restrict__ outB, unsigned short* __restrict__ outB2,
    unsigned short* __restrict__ outVT, float bscale, int N, int K, int ntx) {
  __shared__ alignas(16) unsigned short As[2][64 * 64];
  __shared__ alignas(16) unsigned short Ws[2][64 * 64];
  const int tid = threadIdx.x;
  const int w = tid >> 6, lane = tid & 63;
  const int lq = lane & 15, kg = lane >> 4;
  const int wm = w >> 1, wn = w & 1;
  // XCD-aware bijection: consecutive logical tiles -> same XCD chunk
  const int nwg = gridDim.x, cpx = nwg >> 3, bid = blockIdx.x;
  const int lid = (bid & 7) * cpx + (bid >> 3);
  const int m0 = (lid / ntx) * 64, n0 = (lid % ntx) * 64;

  f32x4 acc[2][2] = {};

  auto STAGE = [&](int buf, int k0) {
#pragma unroll
    for (int i = 0; i < 2; i++) {
      const int li = i * 256 + tid;
      const int row = li >> 3, sl = (li & 7) ^ (row & 7);
      gload_lds16(A + (size_t)(m0 + row) * K + k0 + sl * 8,
                  (char*)As[buf] + (i * 256 + (tid & ~63)) * 16);
    }
#pragma unroll
    for (int i = 0; i < 2; i++) {
      const int li = i * 256 + tid;
      const int row = li >> 3, sl = (li & 7) ^ (row & 7);
      gload_lds16(W + (size_t)(n0 + row) * K + k0 + sl * 8,
                  (char*)Ws[buf] + (i * 256 + (tid & ~63)) * 16);
    }
  };

  const int nt = K >> 6;
  STAGE(0, 0);
  for (int t = 0; t < nt; t++) {
    __syncthreads();  // drains vmcnt -> buf[t&1] ready; all waves past t-1
    if (t + 1 < nt) STAGE((t + 1) & 1, (t + 1) << 6);
    const unsigned short* as = As[t & 1];
    const unsigned short* wsb = Ws[t & 1];
#pragma unroll
    for (int kk = 0; kk < 2; kk++) {
      const int sl = (((kk * 4 + kg) ^ (lq & 7)) << 3);
      u32x4 a0 = *(const u32x4*)&as[((wm * 32 + lq) << 6) + sl];
      u32x4 a1 = *(const u32x4*)&as[((wm * 32 + 16 + lq) << 6) + sl];
      u32x4 b0 = *(const u32x4*)&wsb[((wn * 32 + lq) << 6) + sl];
      u32x4 b1 = *(const u32x4*)&wsb[((wn * 32 + 16 + lq) << 6) + sl];
      __builtin_amdgcn_s_setprio(1);
      acc[0][0] = mfma_bf16(a0, b0, acc[0][0]);
      acc[0][1] = mfma_bf16(a0, b1, acc[0][1]);
      acc[1][0] = mfma_bf16(a1, b0, acc[1][0]);
      acc[1][1] = mfma_bf16(a1, b1, acc[1][1]);
      __builtin_amdgcn_s_setprio(0);
    }
  }

  // Epilogue: D row = kg*4+r, col = lq per 16x16 frag.
  if (outVT && n0 >= 512) {  // V^T path (fused QKV, n-512)
#pragma unroll
    for (int mi = 0; mi < 2; mi++) {
      const int mb = m0 + wm * 32 + mi * 16 + kg * 4;
      const int bq = mb >> 11, s0 = mb & 2047;
#pragma unroll
      for (int nj = 0; nj < 2; nj++) {
        const int nn = n0 - 512 + wn * 32 + nj * 16 + lq;
        const int hh = nn >> 5, dd = nn & 31;
        uint2 pv;
        pv.x = pk2(fmaxf(acc[mi][nj][0], 0.f), fmaxf(acc[mi][nj][1], 0.f));
        pv.y = pk2(fmaxf(acc[mi][nj][2], 0.f), fmaxf(acc[mi][nj][3], 0.f));
        *(uint2*)(outVT + ((size_t)(bq * 8 + hh) * 32 + dd) * 2048 + s0) = pv;
      }
    }
  } else if (outB2 && n0 >= 256) {  // K path (fused QKV, n-256, no scale)
#pragma unroll
    for (int mi = 0; mi < 2; mi++) {
      const int m = m0 + wm * 32 + mi * 16 + kg * 4;
#pragma unroll
      for (int nj = 0; nj < 2; nj++) {
        const int nn = n0 - 256 + wn * 32 + nj * 16 + lq;
#pragma unroll
        for (int r = 0; r < 4; r++)
          outB2[(size_t)(m + r) * 256 + nn] = bf1(fmaxf(acc[mi][nj][r], 0.f));
      }
    }
  } else {
    const int ldo = (outB2 || outVT) ? 256 : N;  // fused-Q path uses 256
#pragma unroll
    for (int mi = 0; mi < 2; mi++) {
      const int m = m0 + wm * 32 + mi * 16 + kg * 4;
#pragma unroll
      for (int nj = 0; nj < 2; nj++) {
        const int n = n0 + wn * 32 + nj * 16 + lq;
#pragma unroll
        for (int r = 0; r < 4; r++) {
          float v = fmaxf(acc[mi][nj][r], 0.f);
          if (res) v += res[(size_t)(m + r) * N + n];
          if (outF) outF[(size_t)(m + r) * N + n] = v;
          if (outB) outB[(size_t)(m + r) * ldo + n] = bf1(v * bscale);
        }
      }
    }
  }
}

// ---------------- MFMA flash attention, fixed-base softmax ----------------
// 4 waves x 16 q rows, 64 keys/step, double-buffered K/V tiles.
// Scores >= 0 (ReLU'd q,k; Q pre-scaled by scale*log2e): P = exp2(sc)
// with no max tracking (softmax normalization cancels any base).
// l computed via ones-row MFMA (consistent with bf16 P numerator).
__global__ __launch_bounds__(256) void attn_mfma_kernel(
    const unsigned short* __restrict__ Q, const unsigned short* __restrict__ K,
    const unsigned short* __restrict__ VT, float* __restrict__ oP,
    float* __restrict__ lP, int nkeys) {
  __shared__ alignas(16) unsigned short Ks[2][64 * 32];  // [key][4 slots x 8]
  __shared__ alignas(16) unsigned short Vt[2][32 * 64];  // [d][8 slots x 8]
  __shared__ alignas(16) unsigned short Ps[4][16][72];

  const int tid = threadIdx.x;
  const int w = tid >> 6;
  const int lane = tid & 63;
  const int lq = lane & 15;
  const int kg = lane >> 4;
  const int bh = blockIdx.y, b = bh >> 3, h = bh & 7;
  const int p = blockIdx.z;
  const int q0 = blockIdx.x * 64 + w * 16;
  const size_t base = (size_t)b * SEQ * DMODEL + h * 32;

  u32x4 qf = *(const u32x4*)(Q + base + (size_t)(q0 + lq) * DMODEL + kg * 8);

  f32x4 oA = {0.f, 0.f, 0.f, 0.f};
  f32x4 oB = {0.f, 0.f, 0.f, 0.f};
  f32x4 lacc = {0.f, 0.f, 0.f, 0.f};
  const unsigned ONE2 = 0x3F803F80u;  // two bf16 1.0
  const u32x4 ones = {ONE2, ONE2, ONE2, ONE2};

  const int kg4 = (lane & 3) ^ ((lane >> 3) & 3);  // K src slot swizzle
  const int vg8 = (lane & 7) ^ (lane >> 3);        // V src slot swizzle
  const unsigned short* vtb = VT + (size_t)bh * 32 * 2048;
  const int kslot = (lq >> 1) & 3;
  const int vslot = lq & 7;

  auto STAGE = [&](int buf, int kt) {
    const int krow = w * 16 + (lane >> 2);
    gload_lds16(K + base + (size_t)(kt + krow) * DMODEL + kg4 * 8,
                (char*)Ks[buf] + w * 1024);
    const int d = w * 8 + (lane >> 3);
    gload_lds16(vtb + (size_t)d * 2048 + kt + vg8 * 8,
                (char*)Vt[buf] + w * 1024);
  };

  const int kbeg = p * nkeys;
  const int nt = nkeys >> 6;
  STAGE(0, kbeg);
  for (int t = 0; t < nt; t++) {
    __syncthreads();
    if (t + 1 < nt) STAGE((t + 1) & 1, kbeg + (t + 1) * 64);
    const unsigned short* ks = Ks[t & 1];
    const unsigned short* vs = Vt[t & 1];

    // QK^T swapped: S[key][q], keys s4*16+kg*4+r at col q=lq
    f32x4 sc[4];
    __builtin_amdgcn_s_setprio(1);
#pragma unroll
    for (int s4 = 0; s4 < 4; s4++) {
      u32x4 ka = *(const u32x4*)&ks[((s4 * 16 + lq) << 5) + ((kg ^ kslot) << 3)];
      f32x4 z = {0.f, 0.f, 0.f, 0.f};
      sc[s4] = mfma_bf16(ka, qf, z);
    }
    __builtin_amdgcn_s_setprio(0);

    // P = exp2(sc) directly (sc >= 0, bounded; base cancels in o/l)
    float pe[16];
#pragma unroll
    for (int s4 = 0; s4 < 4; s4++)
#pragma unroll
      for (int r = 0; r < 4; r++) pe[s4 * 4 + r] = exp2f(sc[s4][r]);

#pragma unroll
    for (int s4 = 0; s4 < 4; s4++) {
      uint2 pw;
      pw.x = pk2(pe[s4 * 4 + 0], pe[s4 * 4 + 1]);
      pw.y = pk2(pe[s4 * 4 + 2], pe[s4 * 4 + 3]);
      *(uint2*)&Ps[w][lq][s4 * 16 + kg * 4] = pw;
    }

    u32x4 pf0 = *(const u32x4*)&Ps[w][lq][kg * 8];
    u32x4 pf1 = *(const u32x4*)&Ps[w][lq][32 + kg * 8];
    u32x4 va00 = *(const u32x4*)&vs[(lq << 6) + ((kg ^ vslot) << 3)];
    u32x4 va01 = *(const u32x4*)&vs[(lq << 6) + (((4 | kg) ^ vslot) << 3)];
    u32x4 va10 = *(const u32x4*)&vs[((16 + lq) << 6) + ((kg ^ vslot) << 3)];
    u32x4 va11 = *(const u32x4*)&vs[((16 + lq) << 6) + (((4 | kg) ^ vslot) << 3)];
    __builtin_amdgcn_s_setprio(1);
    oA = mfma_bf16(va00, pf0, oA);
    oA = mfma_bf16(va01, pf1, oA);
    oB = mfma_bf16(va10, pf0, oB);
    oB = mfma_bf16(va11, pf1, oB);
    lacc = mfma_bf16(ones, pf0, lacc);
    lacc = mfma_bf16(ones, pf1, lacc);
    __builtin_amdgcn_s_setprio(0);
  }

  const int qrow = q0 + lq;
  const size_t sidx = ((size_t)p * 32 + bh) * SEQ + qrow;
  if (kg == 0) lP[sidx] = lacc[0];
  float* op = oP + sidx * 32;
#pragma unroll
  for (int r = 0; r < 4; r++) {
    op[kg * 4 + r] = oA[r];
    op[16 + kg * 4 + r] = oB[r];
  }
}

// Merge NS partial states (consistent base): out = sum(o) / sum(l)
template <int NS>
__global__ __launch_bounds__(256) void attn_combine_kernel(
    const float* __restrict__ oP, const float* __restrict__ lP,
    unsigned short* __restrict__ O) {
  const int t = blockIdx.x * blockDim.x + threadIdx.x;
  const int bh = t >> 11;
  const int qrow = t & 2047;
  const int b = bh >> 3, h = bh & 7;

  float lsum = 0.f;
#pragma unroll
  for (int pp = 0; pp < NS; pp++)
    lsum += lP[((size_t)pp * 32 + bh) * SEQ + qrow];
  const float inv = 1.f / lsum;

  float acc[32] = {};
#pragma unroll
  for (int pp = 0; pp < NS; pp++) {
    const float* op = oP + (((size_t)pp * 32 + bh) * SEQ + qrow) * 32;
#pragma unroll
    for (int i = 0; i < 8; i++) {
      float4 v = *(const float4*)(op + i * 4);
      acc[i * 4 + 0] += v.x;
      acc[i * 4 + 1] += v.y;
      acc[i * 4 + 2] += v.z;
      acc[i * 4 + 3] += v.w;
    }
  }
  unsigned short* outp =
      O + (size_t)b * SEQ * DMODEL + (size_t)qrow * DMODEL + h * 32;
#pragma unroll
  for (int i = 0; i < 8; i++) {
    uint2 v;
    v.x = pk2(acc[i * 4 + 0] * inv, acc[i * 4 + 1] * inv);
    v.y = pk2(acc[i * 4 + 2] * inv, acc[i * 4 + 3] * inv);
    *(uint2*)(outp + i * 4) = v;
  }
}

// ---------------- LayerNorm (256) ----------------
__global__ __launch_bounds__(256) void ln_kernel(
    const float* __restrict__ X, const float* __restrict__ g,
    const float* __restrict__ b, float* __restrict__ Y,
    unsigned short* __restrict__ Yb) {
  const int wid = (blockIdx.x * blockDim.x + threadIdx.x) >> 6;
  const int lane = threadIdx.x & 63;
  const float* x = X + (size_t)wid * DMODEL;
  float4 v = *(const float4*)(x + lane * 4);
  float s = v.x + v.y + v.z + v.w;
  float s2 = v.x * v.x + v.y * v.y + v.z * v.z + v.w * v.w;
#pragma unroll
  for (int off = 32; off >= 1; off >>= 1) {
    s += __shfl_xor(s, off, 64);
    s2 += __shfl_xor(s2, off, 64);
  }
  const float mu = s * (1.f / DMODEL);
  const float var = s2 * (1.f / DMODEL) - mu * mu;
  const float inv = rsqrtf(var + LN_EPS);
  float4 gv = *(const float4*)(g + lane * 4);
  float4 bv = *(const float4*)(b + lane * 4);
  float4 o;
  o.x = (v.x - mu) * inv * gv.x + bv.x;
  o.y = (v.y - mu) * inv * gv.y + bv.y;
  o.z = (v.z - mu) * inv * gv.z + bv.z;
  o.w = (v.w - mu) * inv * gv.w + bv.w;
  if (Y) *(float4*)(Y + (size_t)wid * DMODEL + lane * 4) = o;
  if (Yb) {
    uint2 p;
    p.x = pk2(o.x, o.y);
    p.y = pk2(o.z, o.w);
    *(uint2*)(Yb + (size_t)wid * DMODEL + lane * 4) = p;
  }
}

extern "C" void kernel_launch(void* const* d_in, const int* in_sizes, int n_in,
                              void* d_out, int out_size, void* d_ws, size_t ws_size,
                              hipStream_t stream) {
  const float* x = (const float*)d_in[0];
  const float* g1 = (const float*)d_in[13];
  const float* b1 = (const float*)d_in[14];
  const float* g2 = (const float*)d_in[15];
  const float* b2 = (const float*)d_in[16];
  const float* g3 = (const float*)d_in[17];
  const float* b3 = (const float*)d_in[18];
  const float* g4 = (const float*)d_in[19];
  const float* b4 = (const float*)d_in[20];

  float* out = (float*)d_out;
  float* ws = (float*)d_ws;
  const size_t NM = (size_t)MROWS * DMODEL;
  const size_t ML = (size_t)32 * SEQ;
  const float QSCALE = 0.17677669529663687f * 1.4426950408889634f;

  float* F0 = ws;
  float* F1 = ws + NM;
  char* U = (char*)(ws + 2 * NM);
  float* oP = (float*)U;                       // 2 splits x 65536 x 32 fp32
  unsigned short* fb = (unsigned short*)U;     // 8192x1024 bf16 (disjoint use)
  float* lP = ws + 4 * NM;                     // 2 x 65536 fp32
  unsigned short* xb = (unsigned short*)(lP + 2 * ML);
  unsigned short* qb = xb + NM;
  unsigned short* kb = qb + NM;
  unsigned short* ob = kb + NM;
  unsigned short* nb = ob + NM;
  unsigned short* wb = nb + NM;
  // weights: [q1|k1|v1][q2|k2|v2][o1][o2][f11][f21][f12][f22]
  unsigned short* qkv1 = wb;
  unsigned short* qkv2 = wb + 3 * 65536;
  unsigned short* o1w = wb + 6 * 65536;
  unsigned short* o2w = wb + 7 * 65536;
  unsigned short* f11 = wb + 8 * 65536;
  unsigned short* f21 = f11 + 262144;
  unsigned short* f12 = f21 + 262144;
  unsigned short* f22 = f12 + 262144;
  unsigned short* vt = (unsigned short*)F0;  // aliases F0 (dead then)

  {
    CvtArgs a;
    a.s[0] = x; a.d[0] = xb; a.n4[0] = (int)(NM / 4);
    unsigned short* wd[12] = {qkv1, qkv1 + 65536, qkv1 + 131072, o1w,
                              qkv2, qkv2 + 65536, qkv2 + 131072, o2w,
                              f11, f21, f12, f22};
    for (int i = 0; i < 12; i++) {
      a.s[i + 1] = (const float*)d_in[i + 1];
      a.d[i + 1] = wd[i];
      a.n4[i + 1] = (i < 8) ? 65536 / 4 : 262144 / 4;
    }
    cvt_kernel<<<dim3(256, 13), 256, 0, stream>>>(a);
  }

  auto gemm = [&](const unsigned short* A, const unsigned short* W,
                  const float* res, float* oF, unsigned short* oB,
                  unsigned short* oB2, unsigned short* oVT, float bs,
                  int N, int K) {
    const int ntx = N / 64;
    const int nwg = ntx * (MROWS / 64);
    gemm_bf16_kernel<<<nwg, 256, 0, stream>>>(A, W, res, oF, oB, oB2, oVT,
                                              bs, N, K, ntx);
  };
  auto attn = [&](const unsigned short* Q, const unsigned short* K,
                  const unsigned short* VT, unsigned short* O) {
    attn_mfma_kernel<<<dim3(SEQ / 64, 32, 2), 256, 0, stream>>>(
        Q, K, VT, oP, lP, SEQ / 2);
    attn_combine_kernel<2><<<65536 / 256, 256, 0, stream>>>(oP, lP, O);
  };
  auto ln = [&](const float* X, const float* gm, const float* bt, float* Y,
                unsigned short* Yb) {
    ln_kernel<<<MROWS / 4, 256, 0, stream>>>(X, gm, bt, Y, Yb);
  };

  // ---- Block 1 ----
  gemm(xb, qkv1, nullptr, nullptr, qb, kb, vt, QSCALE, 768, 256);  // QKV
  attn(qb, kb, vt, ob);
  gemm(ob, o1w, x, F0, nullptr, nullptr, nullptr, 1.f, 256, 256);  // x1
  ln(F0, g1, b1, F1, nb);
  gemm(nb, f11, nullptr, nullptr, fb, nullptr, nullptr, 1.f, 1024, 256);
  gemm(fb, f21, F1, F0, nullptr, nullptr, nullptr, 1.f, 256, 1024);
  ln(F0, g2, b2, F1, xb);

  // ---- Block 2 ----
  gemm(xb, qkv2, nullptr, nullptr, qb, kb, vt, QSCALE, 768, 256);
  attn(qb, kb, vt, ob);
  gemm(ob, o2w, F1, F0, nullptr, nullptr, nullptr, 1.f, 256, 256);
  ln(F0, g3, b3, F1, nb);
  gemm(nb, f12, nullptr, nullptr, fb, nullptr, nullptr, 1.f, 1024, 256);
  gemm(fb, f22, F1, F0, nullptr, nullptr, nullptr, 1.f, 256, 1024);
  ln(F0, g4, b4, out, nullptr);
}